// Round 1
// baseline (1863.700 us; speedup 1.0000x reference)
//
#include <hip/hip_runtime.h>
#include <math.h>

#define BB_ 2
#define SS_ 2048
#define DD_ 1024
#define NHEAD_ 16
#define DH_ 64
#define BN_ (BB_*NHEAD_)   // 32
#define BS_ (BB_*SS_)      // 4096

// ---------------- Kernel 1: QKV projections ----------------
// C[m = b*S+s, n = head*64+h] = sum_d resid[m,d] * W[n,d]   (GEMM-NT)
// dst layout: [b, head, s, h]
__global__ __launch_bounds__(256) void qkv_proj_kernel(
    const float* __restrict__ resid,
    const float* __restrict__ WQ,
    const float* __restrict__ WK,
    const float* __restrict__ WV,
    float* __restrict__ q, float* __restrict__ k, float* __restrict__ v)
{
    __shared__ float As[64][65];   // [m][k]  (+1 pad: conflict-free)
    __shared__ float Bs[64][65];   // [k][n]  (transposed on store)
    const int tx = threadIdx.x, ty = threadIdx.y;
    const int tid = ty * 16 + tx;
    const int mBase = blockIdx.x * 64;
    const int nBase = blockIdx.y * 64;
    const float* W = (blockIdx.z == 0) ? WQ : (blockIdx.z == 1 ? WK : WV);
    float* dst = (blockIdx.z == 0) ? q : (blockIdx.z == 1 ? k : v);

    float acc[4][4] = {};
    for (int k0 = 0; k0 < DD_; k0 += 64) {
        #pragma unroll
        for (int i = 0; i < 16; ++i) {
            int idx = i * 256 + tid;
            int r = idx >> 6, c = idx & 63;
            As[r][c] = resid[(mBase + r) * DD_ + k0 + c];   // coalesced
            Bs[c][r] = W[(nBase + r) * DD_ + k0 + c];       // coalesced read, conflict-free store
        }
        __syncthreads();
        #pragma unroll 8
        for (int kk = 0; kk < 64; ++kk) {
            float a[4], b[4];
            #pragma unroll
            for (int i = 0; i < 4; ++i) a[i] = As[ty * 4 + i][kk];   // broadcast groups
            #pragma unroll
            for (int j = 0; j < 4; ++j) b[j] = Bs[kk][tx * 4 + j];
            #pragma unroll
            for (int i = 0; i < 4; ++i) {
                #pragma unroll
                for (int j = 0; j < 4; ++j) acc[i][j] += a[i] * b[j];
            }
        }
        __syncthreads();
    }
    const int head = blockIdx.y;   // n-tile of 64 == one head
    #pragma unroll
    for (int i = 0; i < 4; ++i) {
        int row = mBase + ty * 4 + i;
        int bb = row >> 11;          // / 2048
        int ss = row & 2047;
        #pragma unroll
        for (int j = 0; j < 4; ++j) {
            int h = tx * 4 + j;
            dst[((bb * NHEAD_ + head) * SS_ + ss) * DH_ + h] = acc[i][j];
        }
    }
}

// ---------------- Kernel 2: causal flash attention ----------------
// grid (S/64, B*N); block 256. Wave w owns q-rows [w*16, w*16+16); lane = k-col.
__global__ __launch_bounds__(256) void flash_attn_kernel(
    const float* __restrict__ q, const float* __restrict__ k,
    const float* __restrict__ v, float* __restrict__ attn)
{
    __shared__ float Qs[64][64];   // reads are wave-uniform (broadcast) -> no pad needed
    __shared__ float Ks[64][64];   // XOR-swizzled columns (stride-64 would be 32-way conflict)
    __shared__ float Vs[64][64];   // reads lane-indexed in col -> conflict-free
    __shared__ float Ps[64][64];   // reads broadcast, writes lane-indexed -> fine
    const int tid = threadIdx.x;
    const int lane = tid & 63;
    const int wave = tid >> 6;     // 0..3
    const int R0 = wave * 16;
    const int qTile = blockIdx.x;  // 0..31
    const int bn = blockIdx.y;     // 0..31 = b*16+n
    const int qBase = qTile * 64;
    const float* Qg = q + bn * SS_ * DH_;
    const float* Kg = k + bn * SS_ * DH_;
    const float* Vg = v + bn * SS_ * DH_;

    // load Q tile once, fold in 1/sqrt(64)
    #pragma unroll
    for (int i = 0; i < 16; ++i) {
        int idx = i * 256 + tid;
        int r = idx >> 6, c = idx & 63;
        Qs[r][c] = Qg[(qBase + r) * DH_ + c] * 0.125f;
    }

    float m[16], l[16], o[16];
    #pragma unroll
    for (int i = 0; i < 16; ++i) { m[i] = -INFINITY; l[i] = 0.0f; o[i] = 0.0f; }

    for (int kt = 0; kt <= qTile; ++kt) {
        const int kBase = kt * 64;
        #pragma unroll
        for (int i = 0; i < 16; ++i) {
            int idx = i * 256 + tid;
            int r = idx >> 6, c = idx & 63;
            Ks[r][c ^ (r & 31)] = Kg[(kBase + r) * DH_ + c];
            Vs[r][c]            = Vg[(kBase + r) * DH_ + c];
        }
        __syncthreads();   // covers Qs on first iter too

        // scores: sc[i] = Q[R0+i,:] . K[lane,:]
        float sc[16];
        #pragma unroll
        for (int i = 0; i < 16; ++i) sc[i] = 0.0f;
        #pragma unroll 4
        for (int h = 0; h < 64; ++h) {
            float kh = Ks[lane][h ^ (lane & 31)];
            #pragma unroll
            for (int i = 0; i < 16; ++i) sc[i] += Qs[R0 + i][h] * kh;
        }

        // online softmax per row (wave-wide reductions)
        #pragma unroll
        for (int i = 0; i < 16; ++i) {
            int qpos = qBase + R0 + i;
            int kpos = kBase + lane;
            float si = (kpos <= qpos) ? sc[i] : -INFINITY;
            float mx = si;
            #pragma unroll
            for (int off = 32; off > 0; off >>= 1)
                mx = fmaxf(mx, __shfl_xor(mx, off, 64));
            float mnew = fmaxf(m[i], mx);               // finite: diagonal always unmasked
            float alpha = __expf(m[i] - mnew);          // exp(-inf)=0 first iter
            float p = __expf(si - mnew);                // masked lanes -> 0
            float ps = p;
            #pragma unroll
            for (int off = 32; off > 0; off >>= 1)
                ps += __shfl_xor(ps, off, 64);
            l[i] = l[i] * alpha + ps;
            m[i] = mnew;
            o[i] *= alpha;
            Ps[R0 + i][lane] = p;    // wave-local rows: in-order DS, no barrier needed
        }

        // O[R0+i][lane] += P[R0+i][:] . V[:,lane]
        #pragma unroll 4
        for (int j = 0; j < 64; ++j) {
            float vj = Vs[j][lane];
            #pragma unroll
            for (int i = 0; i < 16; ++i) o[i] += Ps[R0 + i][j] * vj;
        }
        __syncthreads();   // protect Ks/Vs before next tile's load
    }

    #pragma unroll
    for (int i = 0; i < 16; ++i)
        attn[(bn * SS_ + qBase + R0 + i) * DH_ + lane] = o[i] / l[i];
}

// ---------------- Kernel 3: output projection ----------------
// out[bs, d] = sum_{n,h} attn[b,n,s,h] * WO[n*64+h, d]   (GEMM-NN, gathered A)
__global__ __launch_bounds__(256) void out_proj_kernel(
    const float* __restrict__ attn, const float* __restrict__ WO,
    float* __restrict__ out)
{
    __shared__ float As[64][65];   // [m][k]
    __shared__ float Bs[64][65];   // [k][n]
    const int tx = threadIdx.x, ty = threadIdx.y;
    const int tid = ty * 16 + tx;
    const int mBase = blockIdx.x * 64;
    const int nBase = blockIdx.y * 64;

    float acc[4][4] = {};
    for (int kt = 0; kt < 16; ++kt) {          // k-tile of 64 == head kt
        #pragma unroll
        for (int i = 0; i < 16; ++i) {
            int idx = i * 256 + tid;
            int r = idx >> 6, c = idx & 63;
            int row = mBase + r;
            int bb = row >> 11, ss = row & 2047;
            As[r][c] = attn[((bb * NHEAD_ + kt) * SS_ + ss) * DH_ + c];
            Bs[r][c] = WO[(kt * 64 + r) * DD_ + nBase + c];
        }
        __syncthreads();
        #pragma unroll 8
        for (int kk = 0; kk < 64; ++kk) {
            float a[4], b[4];
            #pragma unroll
            for (int i = 0; i < 4; ++i) a[i] = As[ty * 4 + i][kk];
            #pragma unroll
            for (int j = 0; j < 4; ++j) b[j] = Bs[kk][tx * 4 + j];
            #pragma unroll
            for (int i = 0; i < 4; ++i) {
                #pragma unroll
                for (int j = 0; j < 4; ++j) acc[i][j] += a[i] * b[j];
            }
        }
        __syncthreads();
    }
    #pragma unroll
    for (int i = 0; i < 4; ++i) {
        int row = mBase + ty * 4 + i;
        #pragma unroll
        for (int j = 0; j < 4; ++j)
            out[row * DD_ + nBase + tx * 4 + j] = acc[i][j];
    }
}

extern "C" void kernel_launch(void* const* d_in, const int* in_sizes, int n_in,
                              void* d_out, int out_size, void* d_ws, size_t ws_size,
                              hipStream_t stream) {
    const float* resid = (const float*)d_in[0];
    const float* WQ    = (const float*)d_in[1];
    const float* WK    = (const float*)d_in[2];
    const float* WV    = (const float*)d_in[3];
    const float* WO    = (const float*)d_in[4];
    float* out = (float*)d_out;

    const size_t per = (size_t)BN_ * SS_ * DH_;   // 4M floats = 16 MB
    float* q    = (float*)d_ws;
    float* k    = q + per;
    float* v    = k + per;
    float* attn = v + per;                        // total 64 MB of d_ws

    qkv_proj_kernel<<<dim3(BS_ / 64, DD_ / 64, 3), dim3(16, 16), 0, stream>>>(
        resid, WQ, WK, WV, q, k, v);
    flash_attn_kernel<<<dim3(SS_ / 64, BN_), dim3(256), 0, stream>>>(q, k, v, attn);
    out_proj_kernel<<<dim3(BS_ / 64, DD_ / 64), dim3(16, 16), 0, stream>>>(attn, WO, out);
}

// Round 2
// 600.253 us; speedup vs baseline: 3.1049x; 3.1049x over previous
//
#include <hip/hip_runtime.h>
#include <math.h>

// R2: full bf16-MFMA rewrite. Zero-LDS fragment GEMMs, MFMA flash attention
// with frag-ordered LDS P round-trip (m120 pattern). Layouts:
//   A-frag: m=lane&15, k=(lane>>4)*8+j   (8 contig bf16 = 16B load)
//   B-frag: n=lane&15, k=(lane>>4)*8+j
//   C/D:    col(n)=lane&15, row(m)=(lane>>4)*4+reg

#define SS_ 2048
#define DD_ 1024
#define NH_ 16
#define BN_ 32
#define BS_ 4096

typedef __bf16 bf16x8 __attribute__((ext_vector_type(8)));
typedef float floatx4 __attribute__((ext_vector_type(4)));
typedef unsigned short ushortx4 __attribute__((ext_vector_type(4)));

__device__ __forceinline__ unsigned short f2bf(float f) {
    union { float f; unsigned u; } v; v.f = f;
    unsigned r = v.u + 0x7FFFu + ((v.u >> 16) & 1u);   // RNE
    return (unsigned short)(r >> 16);
}

// ---------- K0a: cast resid + WQ/WK/WV to bf16 ----------
__global__ __launch_bounds__(256) void cast_bf16_kernel(
    const float* __restrict__ resid, const float* __restrict__ WQ,
    const float* __restrict__ WK, const float* __restrict__ WV,
    unsigned short* __restrict__ residB, unsigned short* __restrict__ WQb,
    unsigned short* __restrict__ WKb, unsigned short* __restrict__ WVb)
{
    const int z = blockIdx.y;
    if (z > 0 && blockIdx.x >= 1024) return;   // weights are 1M elems, resid 4M
    const float* src = (z == 0) ? resid : (z == 1) ? WQ : (z == 2) ? WK : WV;
    unsigned short* dst = (z == 0) ? residB : (z == 1) ? WQb : (z == 2) ? WKb : WVb;
    const int i = (blockIdx.x * 256 + threadIdx.x) * 4;
    float4 f = *(const float4*)(src + i);
    ushortx4 o;
    o[0] = f2bf(f.x); o[1] = f2bf(f.y); o[2] = f2bf(f.z); o[3] = f2bf(f.w);
    *(ushortx4*)(dst + i) = o;
}

// ---------- K0b: WO [kk=n*64+h][d] fp32 -> WOt [d][kk] bf16 ----------
__global__ __launch_bounds__(256) void wo_transpose_kernel(
    const float* __restrict__ WO, unsigned short* __restrict__ WOt)
{
    __shared__ float t[64][65];
    const int kk0 = blockIdx.x * 64, d0 = blockIdx.y * 64;
    #pragma unroll
    for (int it = 0; it < 16; ++it) {
        int idx = it * 256 + threadIdx.x;
        int r = idx >> 6, c = idx & 63;
        t[r][c] = WO[(kk0 + r) * DD_ + d0 + c];
    }
    __syncthreads();
    #pragma unroll
    for (int it = 0; it < 16; ++it) {
        int idx = it * 256 + threadIdx.x;
        int r = idx >> 6, c = idx & 63;
        WOt[(d0 + r) * DD_ + kk0 + c] = f2bf(t[c][r]);
    }
}

// ---------- K1: QKV projections, zero-LDS MFMA ----------
// C[m][n] = sum_d resid[m,d]*W[n,d]; q/k -> [bn][s][h] bf16 (q pre-scaled 1/8),
// v -> transposed [bn][h][s] bf16 so flash PV B-frags are contiguous.
__global__ __launch_bounds__(256) void qkv_mfma_kernel(
    const unsigned short* __restrict__ residB,
    const unsigned short* __restrict__ WQb,
    const unsigned short* __restrict__ WKb,
    const unsigned short* __restrict__ WVb,
    unsigned short* __restrict__ q, unsigned short* __restrict__ kk,
    unsigned short* __restrict__ vT)
{
    const int z = blockIdx.z;
    const unsigned short* W = (z == 0) ? WQb : (z == 1) ? WKb : WVb;
    unsigned short* dst = (z == 0) ? q : (z == 1) ? kk : vT;
    const int l = threadIdx.x & 63, w = threadIdx.x >> 6;
    const int quad = l >> 4, lan = l & 15;
    const int mBase = blockIdx.x * 128 + w * 32;
    const int head = blockIdx.y;
    const int nBase = head * 64;

    floatx4 acc[2][4];
    #pragma unroll
    for (int a = 0; a < 2; ++a)
        #pragma unroll
        for (int b = 0; b < 4; ++b)
            #pragma unroll
            for (int i = 0; i < 4; ++i) acc[a][b][i] = 0.f;

    const unsigned short* Arow0 = residB + (size_t)(mBase + lan) * DD_ + quad * 8;
    const unsigned short* Brow  = W + (size_t)(nBase + lan) * DD_ + quad * 8;
    #pragma unroll 2
    for (int k0 = 0; k0 < DD_; k0 += 32) {
        bf16x8 A0 = *(const bf16x8*)(Arow0 + k0);
        bf16x8 A1 = *(const bf16x8*)(Arow0 + 16 * DD_ + k0);
        bf16x8 B0 = *(const bf16x8*)(Brow + k0);
        bf16x8 B1 = *(const bf16x8*)(Brow + 16 * DD_ + k0);
        bf16x8 B2 = *(const bf16x8*)(Brow + 32 * DD_ + k0);
        bf16x8 B3 = *(const bf16x8*)(Brow + 48 * DD_ + k0);
        acc[0][0] = __builtin_amdgcn_mfma_f32_16x16x32_bf16(A0, B0, acc[0][0], 0, 0, 0);
        acc[0][1] = __builtin_amdgcn_mfma_f32_16x16x32_bf16(A0, B1, acc[0][1], 0, 0, 0);
        acc[0][2] = __builtin_amdgcn_mfma_f32_16x16x32_bf16(A0, B2, acc[0][2], 0, 0, 0);
        acc[0][3] = __builtin_amdgcn_mfma_f32_16x16x32_bf16(A0, B3, acc[0][3], 0, 0, 0);
        acc[1][0] = __builtin_amdgcn_mfma_f32_16x16x32_bf16(A1, B0, acc[1][0], 0, 0, 0);
        acc[1][1] = __builtin_amdgcn_mfma_f32_16x16x32_bf16(A1, B1, acc[1][1], 0, 0, 0);
        acc[1][2] = __builtin_amdgcn_mfma_f32_16x16x32_bf16(A1, B2, acc[1][2], 0, 0, 0);
        acc[1][3] = __builtin_amdgcn_mfma_f32_16x16x32_bf16(A1, B3, acc[1][3], 0, 0, 0);
    }
    const float scale = (z == 0) ? 0.125f : 1.0f;   // fold 1/sqrt(64) into Q
    #pragma unroll
    for (int mt = 0; mt < 2; ++mt)
        #pragma unroll
        for (int nt = 0; nt < 4; ++nt)
            #pragma unroll
            for (int reg = 0; reg < 4; ++reg) {
                int row = mBase + mt * 16 + quad * 4 + reg;
                int bb = row >> 11, ss = row & 2047;
                int h = nt * 16 + lan;
                unsigned short vb = f2bf(acc[mt][nt][reg] * scale);
                if (z < 2) dst[((size_t)(bb * NH_ + head) * SS_ + ss) * 64 + h] = vb;
                else       dst[((size_t)(bb * NH_ + head) * 64 + h) * SS_ + ss] = vb;
            }
}

// ---------- K2: MFMA flash attention (causal), no __syncthreads ----------
__global__ __launch_bounds__(256) void flash_mfma_kernel(
    const unsigned short* __restrict__ q,
    const unsigned short* __restrict__ k,
    const unsigned short* __restrict__ vT,
    unsigned short* __restrict__ attn)
{
    __shared__ unsigned short Ps[4][2][64][8];   // wave-private, frag-ordered
    const int l = threadIdx.x & 63, w = threadIdx.x >> 6;
    const int quad = l >> 4, lan = l & 15;
    const int qTile = blockIdx.x, bn = blockIdx.y;
    const int qBase = qTile * 64;
    const int qRow0 = qBase + w * 16;

    const unsigned short* Qg = q  + (size_t)bn * SS_ * 64;
    const unsigned short* Kg = k  + (size_t)bn * SS_ * 64;
    const unsigned short* Vg = vT + (size_t)bn * 64 * SS_;

    bf16x8 Qf0 = *(const bf16x8*)(Qg + (size_t)(qRow0 + lan) * 64 + quad * 8);
    bf16x8 Qf1 = *(const bf16x8*)(Qg + (size_t)(qRow0 + lan) * 64 + 32 + quad * 8);

    float mrow[4], lrow[4];
    floatx4 o[4];
    #pragma unroll
    for (int r = 0; r < 4; ++r) { mrow[r] = -INFINITY; lrow[r] = 0.f; }
    #pragma unroll
    for (int t = 0; t < 4; ++t)
        #pragma unroll
        for (int i = 0; i < 4; ++i) o[t][i] = 0.f;

    for (int kt = 0; kt <= qTile; ++kt) {
        const int kBase = kt * 64;
        floatx4 sc[4];
        #pragma unroll
        for (int nt = 0; nt < 4; ++nt) {
            const unsigned short* Kr = Kg + (size_t)(kBase + nt * 16 + lan) * 64 + quad * 8;
            bf16x8 K0 = *(const bf16x8*)(Kr);
            bf16x8 K1 = *(const bf16x8*)(Kr + 32);
            floatx4 zz; zz[0] = zz[1] = zz[2] = zz[3] = 0.f;
            sc[nt] = __builtin_amdgcn_mfma_f32_16x16x32_bf16(Qf0, K0, zz, 0, 0, 0);
            sc[nt] = __builtin_amdgcn_mfma_f32_16x16x32_bf16(Qf1, K1, sc[nt], 0, 0, 0);
        }
        if (kt == qTile) {   // only the diagonal tile needs the causal mask
            #pragma unroll
            for (int nt = 0; nt < 4; ++nt)
                #pragma unroll
                for (int reg = 0; reg < 4; ++reg)
                    if (kBase + nt * 16 + lan > qRow0 + quad * 4 + reg)
                        sc[nt][reg] = -INFINITY;
        }
        // online softmax; row lives in one 16-lane quad -> width-16 shuffles
        float p[4][4], alpha[4];
        #pragma unroll
        for (int reg = 0; reg < 4; ++reg) {
            float mx = fmaxf(fmaxf(sc[0][reg], sc[1][reg]), fmaxf(sc[2][reg], sc[3][reg]));
            #pragma unroll
            for (int off = 1; off < 16; off <<= 1) mx = fmaxf(mx, __shfl_xor(mx, off, 16));
            float mnew = fmaxf(mrow[reg], mx);
            alpha[reg] = __expf(mrow[reg] - mnew);   // first iter: exp(-inf)=0
            float sum = 0.f;
            #pragma unroll
            for (int nt = 0; nt < 4; ++nt) {
                float pp = __expf(sc[nt][reg] - mnew);
                p[nt][reg] = pp; sum += pp;
            }
            #pragma unroll
            for (int off = 1; off < 16; off <<= 1) sum += __shfl_xor(sum, off, 16);
            lrow[reg] = lrow[reg] * alpha[reg] + sum;
            mrow[reg] = mnew;
        }
        #pragma unroll
        for (int t = 0; t < 4; ++t)
            #pragma unroll
            for (int reg = 0; reg < 4; ++reg) o[t][reg] *= alpha[reg];

        // P: C-layout -> A-layout via frag-ordered LDS (wave-private; DS is
        // in-order per wave, so no barrier needed, only a lgkmcnt drain)
        #pragma unroll
        for (int nt = 0; nt < 4; ++nt)
            #pragma unroll
            for (int reg = 0; reg < 4; ++reg) {
                int chunk = (quad * 4 + reg) | ((((nt & 1) << 1) | (lan >> 3)) << 4);
                Ps[w][nt >> 1][chunk][lan & 7] = f2bf(p[nt][reg]);
            }
        asm volatile("s_waitcnt lgkmcnt(0)" ::: "memory");
        bf16x8 Pf0 = *(const bf16x8*)(&Ps[w][0][l][0]);
        bf16x8 Pf1 = *(const bf16x8*)(&Ps[w][1][l][0]);

        #pragma unroll
        for (int t = 0; t < 4; ++t) {
            const unsigned short* Vr = Vg + (size_t)(t * 16 + lan) * SS_ + kBase + quad * 8;
            bf16x8 V0 = *(const bf16x8*)(Vr);
            bf16x8 V1 = *(const bf16x8*)(Vr + 32);
            o[t] = __builtin_amdgcn_mfma_f32_16x16x32_bf16(Pf0, V0, o[t], 0, 0, 0);
            o[t] = __builtin_amdgcn_mfma_f32_16x16x32_bf16(Pf1, V1, o[t], 0, 0, 0);
        }
    }
    #pragma unroll
    for (int t = 0; t < 4; ++t)
        #pragma unroll
        for (int reg = 0; reg < 4; ++reg) {
            int row = qRow0 + quad * 4 + reg;
            attn[((size_t)bn * SS_ + row) * 64 + t * 16 + lan] = f2bf(o[t][reg] / lrow[reg]);
        }
}

// ---------- K3: output projection, zero-LDS MFMA ----------
// out[m][d] = sum_kk attn_gathered[m][kk] * WOt[d][kk]
__global__ __launch_bounds__(256) void out_mfma_kernel(
    const unsigned short* __restrict__ attn,
    const unsigned short* __restrict__ WOt,
    float* __restrict__ out)
{
    const int l = threadIdx.x & 63, w = threadIdx.x >> 6;
    const int quad = l >> 4, lan = l & 15;
    const int mBase = blockIdx.x * 128 + w * 32;
    const int nBase = blockIdx.y * 64;

    floatx4 acc[2][4];
    #pragma unroll
    for (int a = 0; a < 2; ++a)
        #pragma unroll
        for (int b = 0; b < 4; ++b)
            #pragma unroll
            for (int i = 0; i < 4; ++i) acc[a][b][i] = 0.f;

    const int row0 = mBase + lan, row1 = row0 + 16;
    const int bb0 = row0 >> 11, ss0 = row0 & 2047;
    const int bb1 = row1 >> 11, ss1 = row1 & 2047;
    const unsigned short* Brow = WOt + (size_t)(nBase + lan) * DD_ + quad * 8;

    #pragma unroll 2
    for (int k0 = 0; k0 < DD_; k0 += 32) {
        const int head = k0 >> 6, hh = (k0 & 63) + quad * 8;
        bf16x8 A0 = *(const bf16x8*)(attn + ((size_t)(bb0 * NH_ + head) * SS_ + ss0) * 64 + hh);
        bf16x8 A1 = *(const bf16x8*)(attn + ((size_t)(bb1 * NH_ + head) * SS_ + ss1) * 64 + hh);
        bf16x8 B0 = *(const bf16x8*)(Brow + k0);
        bf16x8 B1 = *(const bf16x8*)(Brow + 16 * DD_ + k0);
        bf16x8 B2 = *(const bf16x8*)(Brow + 32 * DD_ + k0);
        bf16x8 B3 = *(const bf16x8*)(Brow + 48 * DD_ + k0);
        acc[0][0] = __builtin_amdgcn_mfma_f32_16x16x32_bf16(A0, B0, acc[0][0], 0, 0, 0);
        acc[0][1] = __builtin_amdgcn_mfma_f32_16x16x32_bf16(A0, B1, acc[0][1], 0, 0, 0);
        acc[0][2] = __builtin_amdgcn_mfma_f32_16x16x32_bf16(A0, B2, acc[0][2], 0, 0, 0);
        acc[0][3] = __builtin_amdgcn_mfma_f32_16x16x32_bf16(A0, B3, acc[0][3], 0, 0, 0);
        acc[1][0] = __builtin_amdgcn_mfma_f32_16x16x32_bf16(A1, B0, acc[1][0], 0, 0, 0);
        acc[1][1] = __builtin_amdgcn_mfma_f32_16x16x32_bf16(A1, B1, acc[1][1], 0, 0, 0);
        acc[1][2] = __builtin_amdgcn_mfma_f32_16x16x32_bf16(A1, B2, acc[1][2], 0, 0, 0);
        acc[1][3] = __builtin_amdgcn_mfma_f32_16x16x32_bf16(A1, B3, acc[1][3], 0, 0, 0);
    }
    #pragma unroll
    for (int mt = 0; mt < 2; ++mt)
        #pragma unroll
        for (int nt = 0; nt < 4; ++nt)
            #pragma unroll
            for (int reg = 0; reg < 4; ++reg) {
                int row = mBase + mt * 16 + quad * 4 + reg;
                out[(size_t)row * DD_ + nBase + nt * 16 + lan] = acc[mt][nt][reg];
            }
}

extern "C" void kernel_launch(void* const* d_in, const int* in_sizes, int n_in,
                              void* d_out, int out_size, void* d_ws, size_t ws_size,
                              hipStream_t stream) {
    const float* resid = (const float*)d_in[0];
    const float* WQ    = (const float*)d_in[1];
    const float* WK    = (const float*)d_in[2];
    const float* WV    = (const float*)d_in[3];
    const float* WO    = (const float*)d_in[4];
    float* out = (float*)d_out;

    // workspace (48 MB of bf16)
    unsigned short* q      = (unsigned short*)d_ws;   // 4M elems each for q,k,vT,attn,residB
    unsigned short* kk     = q      + 4194304;
    unsigned short* vT     = kk     + 4194304;
    unsigned short* attn   = vT     + 4194304;
    unsigned short* residB = attn   + 4194304;
    unsigned short* WQb    = residB + 4194304;        // 1M elems each
    unsigned short* WKb    = WQb    + 1048576;
    unsigned short* WVb    = WKb    + 1048576;
    unsigned short* WOt    = WVb    + 1048576;

    cast_bf16_kernel<<<dim3(4096, 4), 256, 0, stream>>>(
        resid, WQ, WK, WV, residB, WQb, WKb, WVb);
    wo_transpose_kernel<<<dim3(16, 16), 256, 0, stream>>>(WO, WOt);
    qkv_mfma_kernel<<<dim3(32, 16, 3), 256, 0, stream>>>(
        residB, WQb, WKb, WVb, q, kk, vT);
    flash_mfma_kernel<<<dim3(32, 32), 256, 0, stream>>>(q, kk, vT, attn);
    out_mfma_kernel<<<dim3(32, 16), 256, 0, stream>>>(attn, WOt, out);
}

// Round 3
// 500.400 us; speedup vs baseline: 3.7244x; 1.1995x over previous
//
#include <hip/hip_runtime.h>
#include <math.h>

// R3: flash softmax reductions moved from __shfl_xor (LDS pipe, ~120cyc/step,
// serialized chains -> latency-bound, all pipes <10% busy) to DPP butterflies
// on the VALU pipe (quad_perm/row_mirror, 16-lane group == DPP row).
// Also: exp -> exp2 with log2e folded into the Q pre-scale.
// Layouts (verified R2, absmax 7.8e-3):
//   A-frag: m=lane&15, k=(lane>>4)*8+j   (8 contig bf16 = 16B load)
//   B-frag: n=lane&15, k=(lane>>4)*8+j
//   C/D:    col(n)=lane&15, row(m)=(lane>>4)*4+reg

#define SS_ 2048
#define DD_ 1024
#define NH_ 16
#define BN_ 32
#define BS_ 4096

typedef __bf16 bf16x8 __attribute__((ext_vector_type(8)));
typedef float floatx4 __attribute__((ext_vector_type(4)));
typedef unsigned short ushortx4 __attribute__((ext_vector_type(4)));

__device__ __forceinline__ unsigned short f2bf(float f) {
    union { float f; unsigned u; } v; v.f = f;
    unsigned r = v.u + 0x7FFFu + ((v.u >> 16) & 1u);   // RNE
    return (unsigned short)(r >> 16);
}

template<int CTRL>
__device__ __forceinline__ float dppmov(float x) {
    int xi = __builtin_bit_cast(int, x);
    return __builtin_bit_cast(float,
        __builtin_amdgcn_update_dpp(xi, xi, CTRL, 0xF, 0xF, true));
}
// reduce over the 16-lane quad-group (a DPP row): xor1, xor2, half_mirror, mirror
__device__ __forceinline__ float red16_max(float x) {
    x = fmaxf(x, dppmov<0xB1>(x));    // quad_perm [1,0,3,2]
    x = fmaxf(x, dppmov<0x4E>(x));    // quad_perm [2,3,0,1]
    x = fmaxf(x, dppmov<0x141>(x));   // row_half_mirror
    x = fmaxf(x, dppmov<0x140>(x));   // row_mirror
    return x;
}
__device__ __forceinline__ float red16_sum(float x) {
    x += dppmov<0xB1>(x);
    x += dppmov<0x4E>(x);
    x += dppmov<0x141>(x);
    x += dppmov<0x140>(x);
    return x;
}

// ---------- K0a: cast resid + WQ/WK/WV to bf16 ----------
__global__ __launch_bounds__(256) void cast_bf16_kernel(
    const float* __restrict__ resid, const float* __restrict__ WQ,
    const float* __restrict__ WK, const float* __restrict__ WV,
    unsigned short* __restrict__ residB, unsigned short* __restrict__ WQb,
    unsigned short* __restrict__ WKb, unsigned short* __restrict__ WVb)
{
    const int z = blockIdx.y;
    if (z > 0 && blockIdx.x >= 1024) return;
    const float* src = (z == 0) ? resid : (z == 1) ? WQ : (z == 2) ? WK : WV;
    unsigned short* dst = (z == 0) ? residB : (z == 1) ? WQb : (z == 2) ? WKb : WVb;
    const int i = (blockIdx.x * 256 + threadIdx.x) * 4;
    float4 f = *(const float4*)(src + i);
    ushortx4 o;
    o[0] = f2bf(f.x); o[1] = f2bf(f.y); o[2] = f2bf(f.z); o[3] = f2bf(f.w);
    *(ushortx4*)(dst + i) = o;
}

// ---------- K0b: WO [kk=n*64+h][d] fp32 -> WOt [d][kk] bf16 ----------
__global__ __launch_bounds__(256) void wo_transpose_kernel(
    const float* __restrict__ WO, unsigned short* __restrict__ WOt)
{
    __shared__ float t[64][65];
    const int kk0 = blockIdx.x * 64, d0 = blockIdx.y * 64;
    #pragma unroll
    for (int it = 0; it < 16; ++it) {
        int idx = it * 256 + threadIdx.x;
        int r = idx >> 6, c = idx & 63;
        t[r][c] = WO[(kk0 + r) * DD_ + d0 + c];
    }
    __syncthreads();
    #pragma unroll
    for (int it = 0; it < 16; ++it) {
        int idx = it * 256 + threadIdx.x;
        int r = idx >> 6, c = idx & 63;
        WOt[(d0 + r) * DD_ + kk0 + c] = f2bf(t[c][r]);
    }
}

// ---------- K1: QKV projections, zero-LDS MFMA ----------
__global__ __launch_bounds__(256) void qkv_mfma_kernel(
    const unsigned short* __restrict__ residB,
    const unsigned short* __restrict__ WQb,
    const unsigned short* __restrict__ WKb,
    const unsigned short* __restrict__ WVb,
    unsigned short* __restrict__ q, unsigned short* __restrict__ kk,
    unsigned short* __restrict__ vT)
{
    const int z = blockIdx.z;
    const unsigned short* W = (z == 0) ? WQb : (z == 1) ? WKb : WVb;
    unsigned short* dst = (z == 0) ? q : (z == 1) ? kk : vT;
    const int l = threadIdx.x & 63, w = threadIdx.x >> 6;
    const int quad = l >> 4, lan = l & 15;
    const int mBase = blockIdx.x * 128 + w * 32;
    const int head = blockIdx.y;
    const int nBase = head * 64;

    floatx4 acc[2][4];
    #pragma unroll
    for (int a = 0; a < 2; ++a)
        #pragma unroll
        for (int b = 0; b < 4; ++b)
            #pragma unroll
            for (int i = 0; i < 4; ++i) acc[a][b][i] = 0.f;

    const unsigned short* Arow0 = residB + (size_t)(mBase + lan) * DD_ + quad * 8;
    const unsigned short* Brow  = W + (size_t)(nBase + lan) * DD_ + quad * 8;
    #pragma unroll 2
    for (int k0 = 0; k0 < DD_; k0 += 32) {
        bf16x8 A0 = *(const bf16x8*)(Arow0 + k0);
        bf16x8 A1 = *(const bf16x8*)(Arow0 + 16 * DD_ + k0);
        bf16x8 B0 = *(const bf16x8*)(Brow + k0);
        bf16x8 B1 = *(const bf16x8*)(Brow + 16 * DD_ + k0);
        bf16x8 B2 = *(const bf16x8*)(Brow + 32 * DD_ + k0);
        bf16x8 B3 = *(const bf16x8*)(Brow + 48 * DD_ + k0);
        acc[0][0] = __builtin_amdgcn_mfma_f32_16x16x32_bf16(A0, B0, acc[0][0], 0, 0, 0);
        acc[0][1] = __builtin_amdgcn_mfma_f32_16x16x32_bf16(A0, B1, acc[0][1], 0, 0, 0);
        acc[0][2] = __builtin_amdgcn_mfma_f32_16x16x32_bf16(A0, B2, acc[0][2], 0, 0, 0);
        acc[0][3] = __builtin_amdgcn_mfma_f32_16x16x32_bf16(A0, B3, acc[0][3], 0, 0, 0);
        acc[1][0] = __builtin_amdgcn_mfma_f32_16x16x32_bf16(A1, B0, acc[1][0], 0, 0, 0);
        acc[1][1] = __builtin_amdgcn_mfma_f32_16x16x32_bf16(A1, B1, acc[1][1], 0, 0, 0);
        acc[1][2] = __builtin_amdgcn_mfma_f32_16x16x32_bf16(A1, B2, acc[1][2], 0, 0, 0);
        acc[1][3] = __builtin_amdgcn_mfma_f32_16x16x32_bf16(A1, B3, acc[1][3], 0, 0, 0);
    }
    // fold 1/sqrt(64) AND log2(e) into Q so flash can use exp2
    const float scale = (z == 0) ? 0.125f * 1.44269504088896340736f : 1.0f;
    #pragma unroll
    for (int mt = 0; mt < 2; ++mt)
        #pragma unroll
        for (int nt = 0; nt < 4; ++nt)
            #pragma unroll
            for (int reg = 0; reg < 4; ++reg) {
                int row = mBase + mt * 16 + quad * 4 + reg;
                int bb = row >> 11, ss = row & 2047;
                int h = nt * 16 + lan;
                unsigned short vb = f2bf(acc[mt][nt][reg] * scale);
                if (z < 2) dst[((size_t)(bb * NH_ + head) * SS_ + ss) * 64 + h] = vb;
                else       dst[((size_t)(bb * NH_ + head) * 64 + h) * SS_ + ss] = vb;
            }
}

// ---------- K2: MFMA flash attention (causal), DPP softmax ----------
__global__ __launch_bounds__(256) void flash_mfma_kernel(
    const unsigned short* __restrict__ q,
    const unsigned short* __restrict__ k,
    const unsigned short* __restrict__ vT,
    unsigned short* __restrict__ attn)
{
    __shared__ unsigned short Ps[4][2][64][8];   // wave-private, frag-ordered
    const int l = threadIdx.x & 63, w = threadIdx.x >> 6;
    const int quad = l >> 4, lan = l & 15;
    const int qTile = blockIdx.x, bn = blockIdx.y;
    const int qBase = qTile * 64;
    const int qRow0 = qBase + w * 16;

    const unsigned short* Qg = q  + (size_t)bn * SS_ * 64;
    const unsigned short* Kg = k  + (size_t)bn * SS_ * 64;
    const unsigned short* Vg = vT + (size_t)bn * 64 * SS_;

    bf16x8 Qf0 = *(const bf16x8*)(Qg + (size_t)(qRow0 + lan) * 64 + quad * 8);
    bf16x8 Qf1 = *(const bf16x8*)(Qg + (size_t)(qRow0 + lan) * 64 + 32 + quad * 8);

    float mrow[4], lrow[4];
    floatx4 o[4];
    #pragma unroll
    for (int r = 0; r < 4; ++r) { mrow[r] = -INFINITY; lrow[r] = 0.f; }
    #pragma unroll
    for (int t = 0; t < 4; ++t)
        #pragma unroll
        for (int i = 0; i < 4; ++i) o[t][i] = 0.f;

    for (int kt = 0; kt <= qTile; ++kt) {
        const int kBase = kt * 64;
        floatx4 sc[4];
        #pragma unroll
        for (int nt = 0; nt < 4; ++nt) {
            const unsigned short* Kr = Kg + (size_t)(kBase + nt * 16 + lan) * 64 + quad * 8;
            bf16x8 K0 = *(const bf16x8*)(Kr);
            bf16x8 K1 = *(const bf16x8*)(Kr + 32);
            floatx4 zz; zz[0] = zz[1] = zz[2] = zz[3] = 0.f;
            sc[nt] = __builtin_amdgcn_mfma_f32_16x16x32_bf16(Qf0, K0, zz, 0, 0, 0);
            sc[nt] = __builtin_amdgcn_mfma_f32_16x16x32_bf16(Qf1, K1, sc[nt], 0, 0, 0);
        }
        if (kt == qTile) {   // only the diagonal tile needs the causal mask
            #pragma unroll
            for (int nt = 0; nt < 4; ++nt)
                #pragma unroll
                for (int reg = 0; reg < 4; ++reg)
                    if (kBase + nt * 16 + lan > qRow0 + quad * 4 + reg)
                        sc[nt][reg] = -INFINITY;
        }
        // online softmax (base-2 domain); row lives in one 16-lane DPP row
        float p[4][4], alpha[4];
        #pragma unroll
        for (int reg = 0; reg < 4; ++reg) {
            float mx = fmaxf(fmaxf(sc[0][reg], sc[1][reg]), fmaxf(sc[2][reg], sc[3][reg]));
            mx = red16_max(mx);
            float mnew = fmaxf(mrow[reg], mx);
            alpha[reg] = exp2f(mrow[reg] - mnew);   // first iter: exp2(-inf)=0
            float sum = 0.f;
            #pragma unroll
            for (int nt = 0; nt < 4; ++nt) {
                float pp = exp2f(sc[nt][reg] - mnew);
                p[nt][reg] = pp; sum += pp;
            }
            sum = red16_sum(sum);
            lrow[reg] = lrow[reg] * alpha[reg] + sum;
            mrow[reg] = mnew;
        }
        #pragma unroll
        for (int t = 0; t < 4; ++t)
            #pragma unroll
            for (int reg = 0; reg < 4; ++reg) o[t][reg] *= alpha[reg];

        // P: C-layout -> A-layout via frag-ordered LDS (wave-private; DS is
        // in-order per wave, so no barrier needed, only a lgkmcnt drain)
        #pragma unroll
        for (int nt = 0; nt < 4; ++nt)
            #pragma unroll
            for (int reg = 0; reg < 4; ++reg) {
                int chunk = (quad * 4 + reg) | ((((nt & 1) << 1) | (lan >> 3)) << 4);
                Ps[w][nt >> 1][chunk][lan & 7] = f2bf(p[nt][reg]);
            }
        asm volatile("s_waitcnt lgkmcnt(0)" ::: "memory");
        bf16x8 Pf0 = *(const bf16x8*)(&Ps[w][0][l][0]);
        bf16x8 Pf1 = *(const bf16x8*)(&Ps[w][1][l][0]);

        #pragma unroll
        for (int t = 0; t < 4; ++t) {
            const unsigned short* Vr = Vg + (size_t)(t * 16 + lan) * SS_ + kBase + quad * 8;
            bf16x8 V0 = *(const bf16x8*)(Vr);
            bf16x8 V1 = *(const bf16x8*)(Vr + 32);
            o[t] = __builtin_amdgcn_mfma_f32_16x16x32_bf16(Pf0, V0, o[t], 0, 0, 0);
            o[t] = __builtin_amdgcn_mfma_f32_16x16x32_bf16(Pf1, V1, o[t], 0, 0, 0);
        }
    }
    #pragma unroll
    for (int t = 0; t < 4; ++t)
        #pragma unroll
        for (int reg = 0; reg < 4; ++reg) {
            int row = qRow0 + quad * 4 + reg;
            attn[((size_t)bn * SS_ + row) * 64 + t * 16 + lan] = f2bf(o[t][reg] / lrow[reg]);
        }
}

// ---------- K3: output projection, zero-LDS MFMA ----------
__global__ __launch_bounds__(256) void out_mfma_kernel(
    const unsigned short* __restrict__ attn,
    const unsigned short* __restrict__ WOt,
    float* __restrict__ out)
{
    const int l = threadIdx.x & 63, w = threadIdx.x >> 6;
    const int quad = l >> 4, lan = l & 15;
    const int mBase = blockIdx.x * 128 + w * 32;
    const int nBase = blockIdx.y * 64;

    floatx4 acc[2][4];
    #pragma unroll
    for (int a = 0; a < 2; ++a)
        #pragma unroll
        for (int b = 0; b < 4; ++b)
            #pragma unroll
            for (int i = 0; i < 4; ++i) acc[a][b][i] = 0.f;

    const int row0 = mBase + lan, row1 = row0 + 16;
    const int bb0 = row0 >> 11, ss0 = row0 & 2047;
    const int bb1 = row1 >> 11, ss1 = row1 & 2047;
    const unsigned short* Brow = WOt + (size_t)(nBase + lan) * DD_ + quad * 8;

    #pragma unroll 2
    for (int k0 = 0; k0 < DD_; k0 += 32) {
        const int head = k0 >> 6, hh = (k0 & 63) + quad * 8;
        bf16x8 A0 = *(const bf16x8*)(attn + ((size_t)(bb0 * NH_ + head) * SS_ + ss0) * 64 + hh);
        bf16x8 A1 = *(const bf16x8*)(attn + ((size_t)(bb1 * NH_ + head) * SS_ + ss1) * 64 + hh);
        bf16x8 B0 = *(const bf16x8*)(Brow + k0);
        bf16x8 B1 = *(const bf16x8*)(Brow + 16 * DD_ + k0);
        bf16x8 B2 = *(const bf16x8*)(Brow + 32 * DD_ + k0);
        bf16x8 B3 = *(const bf16x8*)(Brow + 48 * DD_ + k0);
        acc[0][0] = __builtin_amdgcn_mfma_f32_16x16x32_bf16(A0, B0, acc[0][0], 0, 0, 0);
        acc[0][1] = __builtin_amdgcn_mfma_f32_16x16x32_bf16(A0, B1, acc[0][1], 0, 0, 0);
        acc[0][2] = __builtin_amdgcn_mfma_f32_16x16x32_bf16(A0, B2, acc[0][2], 0, 0, 0);
        acc[0][3] = __builtin_amdgcn_mfma_f32_16x16x32_bf16(A0, B3, acc[0][3], 0, 0, 0);
        acc[1][0] = __builtin_amdgcn_mfma_f32_16x16x32_bf16(A1, B0, acc[1][0], 0, 0, 0);
        acc[1][1] = __builtin_amdgcn_mfma_f32_16x16x32_bf16(A1, B1, acc[1][1], 0, 0, 0);
        acc[1][2] = __builtin_amdgcn_mfma_f32_16x16x32_bf16(A1, B2, acc[1][2], 0, 0, 0);
        acc[1][3] = __builtin_amdgcn_mfma_f32_16x16x32_bf16(A1, B3, acc[1][3], 0, 0, 0);
    }
    #pragma unroll
    for (int mt = 0; mt < 2; ++mt)
        #pragma unroll
        for (int nt = 0; nt < 4; ++nt)
            #pragma unroll
            for (int reg = 0; reg < 4; ++reg) {
                int row = mBase + mt * 16 + quad * 4 + reg;
                out[(size_t)row * DD_ + nBase + nt * 16 + lan] = acc[mt][nt][reg];
            }
}

extern "C" void kernel_launch(void* const* d_in, const int* in_sizes, int n_in,
                              void* d_out, int out_size, void* d_ws, size_t ws_size,
                              hipStream_t stream) {
    const float* resid = (const float*)d_in[0];
    const float* WQ    = (const float*)d_in[1];
    const float* WK    = (const float*)d_in[2];
    const float* WV    = (const float*)d_in[3];
    const float* WO    = (const float*)d_in[4];
    float* out = (float*)d_out;

    unsigned short* q      = (unsigned short*)d_ws;
    unsigned short* kk     = q      + 4194304;
    unsigned short* vT     = kk     + 4194304;
    unsigned short* attn   = vT     + 4194304;
    unsigned short* residB = attn   + 4194304;
    unsigned short* WQb    = residB + 4194304;
    unsigned short* WKb    = WQb    + 1048576;
    unsigned short* WVb    = WKb    + 1048576;
    unsigned short* WOt    = WVb    + 1048576;

    cast_bf16_kernel<<<dim3(4096, 4), 256, 0, stream>>>(
        resid, WQ, WK, WV, residB, WQb, WKb, WVb);
    wo_transpose_kernel<<<dim3(16, 16), 256, 0, stream>>>(WO, WOt);
    qkv_mfma_kernel<<<dim3(32, 16, 3), 256, 0, stream>>>(
        residB, WQb, WKb, WVb, q, kk, vT);
    flash_mfma_kernel<<<dim3(32, 32), 256, 0, stream>>>(q, kk, vT, attn);
    out_mfma_kernel<<<dim3(32, 16), 256, 0, stream>>>(attn, WOt, out);
}

// Round 4
// 454.081 us; speedup vs baseline: 4.1043x; 1.1020x over previous
//
#include <hip/hip_runtime.h>
#include <math.h>

// R4 flash rewrite: S^T = K.Q^T so softmax state is per-lane scalar and P^T
// lands directly in the B-frag layout of mfma_16x16x16_bf16 -> no LDS
// round-trip, no asm memory clobber, pure dataflow loop. Grid pair-balanced:
// block p handles q-tiles {p, 31-p} = 33 k-iterations for every block.
// Layouts (verified R2/R3, absmax 7.8e-3):
//   x32 A-frag: m=lane&15, k=(lane>>4)*8+j ; B-frag: n=lane&15, k=(lane>>4)*8+j
//   x16 A/B-frag: idx=lane&15, k=(lane>>4)*4+j
//   C/D (all 16x16): col=lane&15, row=(lane>>4)*4+reg

#define SS_ 2048
#define DD_ 1024
#define NH_ 16
#define BN_ 32
#define BS_ 4096

typedef __bf16 bf16x8 __attribute__((ext_vector_type(8)));
typedef __bf16 bf16x4 __attribute__((ext_vector_type(4)));
typedef short shortx4 __attribute__((ext_vector_type(4)));
typedef float floatx4 __attribute__((ext_vector_type(4)));
typedef unsigned short ushortx4 __attribute__((ext_vector_type(4)));

__device__ __forceinline__ unsigned short f2bf(float f) {
    union { float f; unsigned u; } v; v.f = f;
    unsigned r = v.u + 0x7FFFu + ((v.u >> 16) & 1u);   // RNE
    return (unsigned short)(r >> 16);
}
__device__ __forceinline__ __bf16 f2bf16(float f) {
    unsigned short u = f2bf(f);
    return __builtin_bit_cast(__bf16, u);
}

__device__ __forceinline__ floatx4 mfma_pv(bf16x4 a, bf16x4 b, floatx4 c) {
#if __has_builtin(__builtin_amdgcn_mfma_f32_16x16x16_bf16)
    return __builtin_amdgcn_mfma_f32_16x16x16_bf16(a, b, c, 0, 0, 0);
#else
    return __builtin_amdgcn_mfma_f32_16x16x16bf16_1k(
        __builtin_bit_cast(shortx4, a), __builtin_bit_cast(shortx4, b), c, 0, 0, 0);
#endif
}

// ---------- K0a: cast resid + WQ/WK/WV to bf16 ----------
__global__ __launch_bounds__(256) void cast_bf16_kernel(
    const float* __restrict__ resid, const float* __restrict__ WQ,
    const float* __restrict__ WK, const float* __restrict__ WV,
    unsigned short* __restrict__ residB, unsigned short* __restrict__ WQb,
    unsigned short* __restrict__ WKb, unsigned short* __restrict__ WVb)
{
    const int z = blockIdx.y;
    if (z > 0 && blockIdx.x >= 1024) return;
    const float* src = (z == 0) ? resid : (z == 1) ? WQ : (z == 2) ? WK : WV;
    unsigned short* dst = (z == 0) ? residB : (z == 1) ? WQb : (z == 2) ? WKb : WVb;
    const int i = (blockIdx.x * 256 + threadIdx.x) * 4;
    float4 f = *(const float4*)(src + i);
    ushortx4 o;
    o[0] = f2bf(f.x); o[1] = f2bf(f.y); o[2] = f2bf(f.z); o[3] = f2bf(f.w);
    *(ushortx4*)(dst + i) = o;
}

// ---------- K0b: WO [kk=n*64+h][d] fp32 -> WOt [d][kk] bf16 ----------
__global__ __launch_bounds__(256) void wo_transpose_kernel(
    const float* __restrict__ WO, unsigned short* __restrict__ WOt)
{
    __shared__ float t[64][65];
    const int kk0 = blockIdx.x * 64, d0 = blockIdx.y * 64;
    #pragma unroll
    for (int it = 0; it < 16; ++it) {
        int idx = it * 256 + threadIdx.x;
        int r = idx >> 6, c = idx & 63;
        t[r][c] = WO[(kk0 + r) * DD_ + d0 + c];
    }
    __syncthreads();
    #pragma unroll
    for (int it = 0; it < 16; ++it) {
        int idx = it * 256 + threadIdx.x;
        int r = idx >> 6, c = idx & 63;
        WOt[(d0 + r) * DD_ + kk0 + c] = f2bf(t[c][r]);
    }
}

// ---------- K1: QKV projections, zero-LDS MFMA ----------
__global__ __launch_bounds__(256) void qkv_mfma_kernel(
    const unsigned short* __restrict__ residB,
    const unsigned short* __restrict__ WQb,
    const unsigned short* __restrict__ WKb,
    const unsigned short* __restrict__ WVb,
    unsigned short* __restrict__ q, unsigned short* __restrict__ kk,
    unsigned short* __restrict__ vT)
{
    const int z = blockIdx.z;
    const unsigned short* W = (z == 0) ? WQb : (z == 1) ? WKb : WVb;
    unsigned short* dst = (z == 0) ? q : (z == 1) ? kk : vT;
    const int l = threadIdx.x & 63, w = threadIdx.x >> 6;
    const int quad = l >> 4, lan = l & 15;
    const int mBase = blockIdx.x * 128 + w * 32;
    const int head = blockIdx.y;
    const int nBase = head * 64;

    floatx4 acc[2][4];
    #pragma unroll
    for (int a = 0; a < 2; ++a)
        #pragma unroll
        for (int b = 0; b < 4; ++b)
            #pragma unroll
            for (int i = 0; i < 4; ++i) acc[a][b][i] = 0.f;

    const unsigned short* Arow0 = residB + (size_t)(mBase + lan) * DD_ + quad * 8;
    const unsigned short* Brow  = W + (size_t)(nBase + lan) * DD_ + quad * 8;
    #pragma unroll 2
    for (int k0 = 0; k0 < DD_; k0 += 32) {
        bf16x8 A0 = *(const bf16x8*)(Arow0 + k0);
        bf16x8 A1 = *(const bf16x8*)(Arow0 + 16 * DD_ + k0);
        bf16x8 B0 = *(const bf16x8*)(Brow + k0);
        bf16x8 B1 = *(const bf16x8*)(Brow + 16 * DD_ + k0);
        bf16x8 B2 = *(const bf16x8*)(Brow + 32 * DD_ + k0);
        bf16x8 B3 = *(const bf16x8*)(Brow + 48 * DD_ + k0);
        acc[0][0] = __builtin_amdgcn_mfma_f32_16x16x32_bf16(A0, B0, acc[0][0], 0, 0, 0);
        acc[0][1] = __builtin_amdgcn_mfma_f32_16x16x32_bf16(A0, B1, acc[0][1], 0, 0, 0);
        acc[0][2] = __builtin_amdgcn_mfma_f32_16x16x32_bf16(A0, B2, acc[0][2], 0, 0, 0);
        acc[0][3] = __builtin_amdgcn_mfma_f32_16x16x32_bf16(A0, B3, acc[0][3], 0, 0, 0);
        acc[1][0] = __builtin_amdgcn_mfma_f32_16x16x32_bf16(A1, B0, acc[1][0], 0, 0, 0);
        acc[1][1] = __builtin_amdgcn_mfma_f32_16x16x32_bf16(A1, B1, acc[1][1], 0, 0, 0);
        acc[1][2] = __builtin_amdgcn_mfma_f32_16x16x32_bf16(A1, B2, acc[1][2], 0, 0, 0);
        acc[1][3] = __builtin_amdgcn_mfma_f32_16x16x32_bf16(A1, B3, acc[1][3], 0, 0, 0);
    }
    // fold 1/sqrt(64) AND log2(e) into Q so flash can use exp2
    const float scale = (z == 0) ? 0.125f * 1.44269504088896340736f : 1.0f;
    #pragma unroll
    for (int mt = 0; mt < 2; ++mt)
        #pragma unroll
        for (int nt = 0; nt < 4; ++nt)
            #pragma unroll
            for (int reg = 0; reg < 4; ++reg) {
                int row = mBase + mt * 16 + quad * 4 + reg;
                int bb = row >> 11, ss = row & 2047;
                int h = nt * 16 + lan;
                unsigned short vb = f2bf(acc[mt][nt][reg] * scale);
                if (z < 2) dst[((size_t)(bb * NH_ + head) * SS_ + ss) * 64 + h] = vb;
                else       dst[((size_t)(bb * NH_ + head) * 64 + h) * SS_ + ss] = vb;
            }
}

// ---------- K2: flash attention, transposed scores, zero LDS ----------
__global__ __launch_bounds__(256) void flash_mfma_kernel(
    const unsigned short* __restrict__ q,
    const unsigned short* __restrict__ k,
    const unsigned short* __restrict__ vT,
    unsigned short* __restrict__ attn)
{
    const int l = threadIdx.x & 63, w = threadIdx.x >> 6;
    const int quad = l >> 4, lan = l & 15;
    const int bn = blockIdx.y;
    const unsigned short* Qg = q  + (size_t)bn * SS_ * 64;
    const unsigned short* Kg = k  + (size_t)bn * SS_ * 64;
    const unsigned short* Vg = vT + (size_t)bn * 64 * SS_;

    #pragma unroll
    for (int half = 0; half < 2; ++half) {
        const int qTile = (half == 0) ? (int)blockIdx.x : 31 - (int)blockIdx.x;
        const int qBase = qTile * 64;
        const int qRow0 = qBase + w * 16;
        const int qAbs = qRow0 + lan;          // this lane's q-row (S^T column)

        bf16x8 Qf0 = *(const bf16x8*)(Qg + (size_t)(qRow0 + lan) * 64 + quad * 8);
        bf16x8 Qf1 = *(const bf16x8*)(Qg + (size_t)(qRow0 + lan) * 64 + 32 + quad * 8);

        float mrow = -INFINITY, lrow = 0.f;
        floatx4 o[4];
        #pragma unroll
        for (int t = 0; t < 4; ++t)
            #pragma unroll
            for (int i = 0; i < 4; ++i) o[t][i] = 0.f;

        for (int kt = 0; kt <= qTile; ++kt) {
            const int kBase = kt * 64;
            // S^T[k][q] = K . Q^T  (same frags as before, operands swapped)
            floatx4 sc[4];
            #pragma unroll
            for (int nt = 0; nt < 4; ++nt) {
                const unsigned short* Kr = Kg + (size_t)(kBase + nt * 16 + lan) * 64 + quad * 8;
                bf16x8 K0 = *(const bf16x8*)(Kr);
                bf16x8 K1 = *(const bf16x8*)(Kr + 32);
                floatx4 zz; zz[0] = zz[1] = zz[2] = zz[3] = 0.f;
                sc[nt] = __builtin_amdgcn_mfma_f32_16x16x32_bf16(K0, Qf0, zz, 0, 0, 0);
                sc[nt] = __builtin_amdgcn_mfma_f32_16x16x32_bf16(K1, Qf1, sc[nt], 0, 0, 0);
            }
            if (kt == qTile) {   // diagonal tile: mask k > q
                #pragma unroll
                for (int nt = 0; nt < 4; ++nt)
                    #pragma unroll
                    for (int reg = 0; reg < 4; ++reg)
                        if (kBase + nt * 16 + quad * 4 + reg > qAbs)
                            sc[nt][reg] = -INFINITY;
            }
            // per-lane softmax state; reduce 16 in-register + 2 shfl steps
            float mx = sc[0][0];
            #pragma unroll
            for (int nt = 0; nt < 4; ++nt)
                #pragma unroll
                for (int reg = 0; reg < 4; ++reg) mx = fmaxf(mx, sc[nt][reg]);
            mx = fmaxf(mx, __shfl_xor(mx, 16, 64));
            mx = fmaxf(mx, __shfl_xor(mx, 32, 64));
            const float mnew = fmaxf(mrow, mx);
            const float alpha = exp2f(mrow - mnew);   // first iter: exp2(-inf)=0
            bf16x4 pb[4];
            float sum = 0.f;
            #pragma unroll
            for (int nt = 0; nt < 4; ++nt)
                #pragma unroll
                for (int reg = 0; reg < 4; ++reg) {
                    float pp = exp2f(sc[nt][reg] - mnew);
                    sum += pp;
                    pb[nt][reg] = f2bf16(pp);         // B-frag: k=quad*4+reg, n=lan
                }
            sum += __shfl_xor(sum, 16, 64);
            sum += __shfl_xor(sum, 32, 64);
            lrow = lrow * alpha + sum;
            mrow = mnew;
            #pragma unroll
            for (int t = 0; t < 4; ++t)
                #pragma unroll
                for (int i = 0; i < 4; ++i) o[t][i] *= alpha;
            // O^T = V^T . P^T : 16x16x16 MFMAs, V^T A-frags straight from vT
            #pragma unroll
            for (int t = 0; t < 4; ++t) {
                const unsigned short* Vr = Vg + (size_t)(t * 16 + lan) * SS_ + kBase + quad * 4;
                #pragma unroll
                for (int nt = 0; nt < 4; ++nt) {
                    bf16x4 Vf = *(const bf16x4*)(Vr + nt * 16);
                    o[t] = mfma_pv(Vf, pb[nt], o[t]);
                }
            }
        }
        // o[t][reg] = O[q=qAbs][h=t*16+quad*4+reg]; 4 regs = 8B contiguous store
        const float rl = 1.f / lrow;
        #pragma unroll
        for (int t = 0; t < 4; ++t) {
            bf16x4 ob;
            #pragma unroll
            for (int reg = 0; reg < 4; ++reg) ob[reg] = f2bf16(o[t][reg] * rl);
            *(bf16x4*)(attn + ((size_t)bn * SS_ + qAbs) * 64 + t * 16 + quad * 4) = ob;
        }
    }
}

// ---------- K3: output projection, zero-LDS MFMA ----------
__global__ __launch_bounds__(256) void out_mfma_kernel(
    const unsigned short* __restrict__ attn,
    const unsigned short* __restrict__ WOt,
    float* __restrict__ out)
{
    const int l = threadIdx.x & 63, w = threadIdx.x >> 6;
    const int quad = l >> 4, lan = l & 15;
    const int mBase = blockIdx.x * 128 + w * 32;
    const int nBase = blockIdx.y * 64;

    floatx4 acc[2][4];
    #pragma unroll
    for (int a = 0; a < 2; ++a)
        #pragma unroll
        for (int b = 0; b < 4; ++b)
            #pragma unroll
            for (int i = 0; i < 4; ++i) acc[a][b][i] = 0.f;

    const int row0 = mBase + lan, row1 = row0 + 16;
    const int bb0 = row0 >> 11, ss0 = row0 & 2047;
    const int bb1 = row1 >> 11, ss1 = row1 & 2047;
    const unsigned short* Brow = WOt + (size_t)(nBase + lan) * DD_ + quad * 8;

    #pragma unroll 2
    for (int k0 = 0; k0 < DD_; k0 += 32) {
        const int head = k0 >> 6, hh = (k0 & 63) + quad * 8;
        bf16x8 A0 = *(const bf16x8*)(attn + ((size_t)(bb0 * NH_ + head) * SS_ + ss0) * 64 + hh);
        bf16x8 A1 = *(const bf16x8*)(attn + ((size_t)(bb1 * NH_ + head) * SS_ + ss1) * 64 + hh);
        bf16x8 B0 = *(const bf16x8*)(Brow + k0);
        bf16x8 B1 = *(const bf16x8*)(Brow + 16 * DD_ + k0);
        bf16x8 B2 = *(const bf16x8*)(Brow + 32 * DD_ + k0);
        bf16x8 B3 = *(const bf16x8*)(Brow + 48 * DD_ + k0);
        acc[0][0] = __builtin_amdgcn_mfma_f32_16x16x32_bf16(A0, B0, acc[0][0], 0, 0, 0);
        acc[0][1] = __builtin_amdgcn_mfma_f32_16x16x32_bf16(A0, B1, acc[0][1], 0, 0, 0);
        acc[0][2] = __builtin_amdgcn_mfma_f32_16x16x32_bf16(A0, B2, acc[0][2], 0, 0, 0);
        acc[0][3] = __builtin_amdgcn_mfma_f32_16x16x32_bf16(A0, B3, acc[0][3], 0, 0, 0);
        acc[1][0] = __builtin_amdgcn_mfma_f32_16x16x32_bf16(A1, B0, acc[1][0], 0, 0, 0);
        acc[1][1] = __builtin_amdgcn_mfma_f32_16x16x32_bf16(A1, B1, acc[1][1], 0, 0, 0);
        acc[1][2] = __builtin_amdgcn_mfma_f32_16x16x32_bf16(A1, B2, acc[1][2], 0, 0, 0);
        acc[1][3] = __builtin_amdgcn_mfma_f32_16x16x32_bf16(A1, B3, acc[1][3], 0, 0, 0);
    }
    #pragma unroll
    for (int mt = 0; mt < 2; ++mt)
        #pragma unroll
        for (int nt = 0; nt < 4; ++nt)
            #pragma unroll
            for (int reg = 0; reg < 4; ++reg) {
                int row = mBase + mt * 16 + quad * 4 + reg;
                out[(size_t)row * DD_ + nBase + nt * 16 + lan] = acc[mt][nt][reg];
            }
}

extern "C" void kernel_launch(void* const* d_in, const int* in_sizes, int n_in,
                              void* d_out, int out_size, void* d_ws, size_t ws_size,
                              hipStream_t stream) {
    const float* resid = (const float*)d_in[0];
    const float* WQ    = (const float*)d_in[1];
    const float* WK    = (const float*)d_in[2];
    const float* WV    = (const float*)d_in[3];
    const float* WO    = (const float*)d_in[4];
    float* out = (float*)d_out;

    unsigned short* q      = (unsigned short*)d_ws;
    unsigned short* kk     = q      + 4194304;
    unsigned short* vT     = kk     + 4194304;
    unsigned short* attn   = vT     + 4194304;
    unsigned short* residB = attn   + 4194304;
    unsigned short* WQb    = residB + 4194304;
    unsigned short* WKb    = WQb    + 1048576;
    unsigned short* WVb    = WKb    + 1048576;
    unsigned short* WOt    = WVb    + 1048576;

    cast_bf16_kernel<<<dim3(4096, 4), 256, 0, stream>>>(
        resid, WQ, WK, WV, residB, WQb, WKb, WVb);
    wo_transpose_kernel<<<dim3(16, 16), 256, 0, stream>>>(WO, WOt);
    qkv_mfma_kernel<<<dim3(32, 16, 3), 256, 0, stream>>>(
        residB, WQb, WKb, WVb, q, kk, vT);
    flash_mfma_kernel<<<dim3(16, 32), 256, 0, stream>>>(q, kk, vT, attn);
    out_mfma_kernel<<<dim3(32, 16), 256, 0, stream>>>(attn, WOt, out);
}

// Round 5
// 353.787 us; speedup vs baseline: 5.2679x; 1.2835x over previous
//
#include <hip/hip_runtime.h>
#include <math.h>

// R5: flash attention restructured around LDS-staged K/V tiles
// (global_load_lds width=16, double-buffered, xor-swizzled rows so the
// contiguous-LDS constraint still gives conflict-free frag reads),
// XCD-aware block swizzle (all blocks of a bn -> same XCD L2), 2-wave
// blocks with 32 q-rows/wave, pair-balanced (p, 31-p) -> 33 iters/block.
// Per-lane MFMA math identical to R4 (verified, absmax 7.8e-3).
// Layouts:
//   x32 A-frag: m=lane&15, k=(lane>>4)*8+j ; B-frag: n=lane&15, k=(lane>>4)*8+j
//   x16 A/B-frag: idx=lane&15, k=(lane>>4)*4+j
//   C/D (all 16x16): col=lane&15, row=(lane>>4)*4+reg

#define SS_ 2048
#define DD_ 1024
#define NH_ 16
#define BN_ 32
#define BS_ 4096

typedef __bf16 bf16x8 __attribute__((ext_vector_type(8)));
typedef __bf16 bf16x4 __attribute__((ext_vector_type(4)));
typedef short shortx4 __attribute__((ext_vector_type(4)));
typedef float floatx4 __attribute__((ext_vector_type(4)));
typedef unsigned short ushortx4 __attribute__((ext_vector_type(4)));

__device__ __forceinline__ unsigned short f2bf(float f) {
    union { float f; unsigned u; } v; v.f = f;
    unsigned r = v.u + 0x7FFFu + ((v.u >> 16) & 1u);   // RNE
    return (unsigned short)(r >> 16);
}
__device__ __forceinline__ __bf16 f2bf16(float f) {
    unsigned short u = f2bf(f);
    return __builtin_bit_cast(__bf16, u);
}

__device__ __forceinline__ floatx4 mfma_pv(bf16x4 a, bf16x4 b, floatx4 c) {
#if __has_builtin(__builtin_amdgcn_mfma_f32_16x16x16_bf16)
    return __builtin_amdgcn_mfma_f32_16x16x16_bf16(a, b, c, 0, 0, 0);
#else
    return __builtin_amdgcn_mfma_f32_16x16x16bf16_1k(
        __builtin_bit_cast(shortx4, a), __builtin_bit_cast(shortx4, b), c, 0, 0, 0);
#endif
}

__device__ __forceinline__ void gl_lds16(const unsigned short* g, unsigned short* l) {
    __builtin_amdgcn_global_load_lds(
        (const __attribute__((address_space(1))) unsigned int*)g,
        (__attribute__((address_space(3))) unsigned int*)l, 16, 0, 0);
}

// ---------- K0a: cast resid + WQ/WK/WV to bf16 ----------
__global__ __launch_bounds__(256) void cast_bf16_kernel(
    const float* __restrict__ resid, const float* __restrict__ WQ,
    const float* __restrict__ WK, const float* __restrict__ WV,
    unsigned short* __restrict__ residB, unsigned short* __restrict__ WQb,
    unsigned short* __restrict__ WKb, unsigned short* __restrict__ WVb)
{
    const int z = blockIdx.y;
    if (z > 0 && blockIdx.x >= 1024) return;
    const float* src = (z == 0) ? resid : (z == 1) ? WQ : (z == 2) ? WK : WV;
    unsigned short* dst = (z == 0) ? residB : (z == 1) ? WQb : (z == 2) ? WKb : WVb;
    const int i = (blockIdx.x * 256 + threadIdx.x) * 4;
    float4 f = *(const float4*)(src + i);
    ushortx4 o;
    o[0] = f2bf(f.x); o[1] = f2bf(f.y); o[2] = f2bf(f.z); o[3] = f2bf(f.w);
    *(ushortx4*)(dst + i) = o;
}

// ---------- K0b: WO [kk=n*64+h][d] fp32 -> WOt [d][kk] bf16 ----------
__global__ __launch_bounds__(256) void wo_transpose_kernel(
    const float* __restrict__ WO, unsigned short* __restrict__ WOt)
{
    __shared__ float t[64][65];
    const int kk0 = blockIdx.x * 64, d0 = blockIdx.y * 64;
    #pragma unroll
    for (int it = 0; it < 16; ++it) {
        int idx = it * 256 + threadIdx.x;
        int r = idx >> 6, c = idx & 63;
        t[r][c] = WO[(kk0 + r) * DD_ + d0 + c];
    }
    __syncthreads();
    #pragma unroll
    for (int it = 0; it < 16; ++it) {
        int idx = it * 256 + threadIdx.x;
        int r = idx >> 6, c = idx & 63;
        WOt[(d0 + r) * DD_ + kk0 + c] = f2bf(t[c][r]);
    }
}

// ---------- K1: QKV projections, zero-LDS MFMA ----------
__global__ __launch_bounds__(256) void qkv_mfma_kernel(
    const unsigned short* __restrict__ residB,
    const unsigned short* __restrict__ WQb,
    const unsigned short* __restrict__ WKb,
    const unsigned short* __restrict__ WVb,
    unsigned short* __restrict__ q, unsigned short* __restrict__ kk,
    unsigned short* __restrict__ vT)
{
    const int z = blockIdx.z;
    const unsigned short* W = (z == 0) ? WQb : (z == 1) ? WKb : WVb;
    unsigned short* dst = (z == 0) ? q : (z == 1) ? kk : vT;
    const int l = threadIdx.x & 63, w = threadIdx.x >> 6;
    const int quad = l >> 4, lan = l & 15;
    const int mBase = blockIdx.x * 128 + w * 32;
    const int head = blockIdx.y;
    const int nBase = head * 64;

    floatx4 acc[2][4];
    #pragma unroll
    for (int a = 0; a < 2; ++a)
        #pragma unroll
        for (int b = 0; b < 4; ++b)
            #pragma unroll
            for (int i = 0; i < 4; ++i) acc[a][b][i] = 0.f;

    const unsigned short* Arow0 = residB + (size_t)(mBase + lan) * DD_ + quad * 8;
    const unsigned short* Brow  = W + (size_t)(nBase + lan) * DD_ + quad * 8;
    #pragma unroll 2
    for (int k0 = 0; k0 < DD_; k0 += 32) {
        bf16x8 A0 = *(const bf16x8*)(Arow0 + k0);
        bf16x8 A1 = *(const bf16x8*)(Arow0 + 16 * DD_ + k0);
        bf16x8 B0 = *(const bf16x8*)(Brow + k0);
        bf16x8 B1 = *(const bf16x8*)(Brow + 16 * DD_ + k0);
        bf16x8 B2 = *(const bf16x8*)(Brow + 32 * DD_ + k0);
        bf16x8 B3 = *(const bf16x8*)(Brow + 48 * DD_ + k0);
        acc[0][0] = __builtin_amdgcn_mfma_f32_16x16x32_bf16(A0, B0, acc[0][0], 0, 0, 0);
        acc[0][1] = __builtin_amdgcn_mfma_f32_16x16x32_bf16(A0, B1, acc[0][1], 0, 0, 0);
        acc[0][2] = __builtin_amdgcn_mfma_f32_16x16x32_bf16(A0, B2, acc[0][2], 0, 0, 0);
        acc[0][3] = __builtin_amdgcn_mfma_f32_16x16x32_bf16(A0, B3, acc[0][3], 0, 0, 0);
        acc[1][0] = __builtin_amdgcn_mfma_f32_16x16x32_bf16(A1, B0, acc[1][0], 0, 0, 0);
        acc[1][1] = __builtin_amdgcn_mfma_f32_16x16x32_bf16(A1, B1, acc[1][1], 0, 0, 0);
        acc[1][2] = __builtin_amdgcn_mfma_f32_16x16x32_bf16(A1, B2, acc[1][2], 0, 0, 0);
        acc[1][3] = __builtin_amdgcn_mfma_f32_16x16x32_bf16(A1, B3, acc[1][3], 0, 0, 0);
    }
    // fold 1/sqrt(64) AND log2(e) into Q so flash can use exp2
    const float scale = (z == 0) ? 0.125f * 1.44269504088896340736f : 1.0f;
    #pragma unroll
    for (int mt = 0; mt < 2; ++mt)
        #pragma unroll
        for (int nt = 0; nt < 4; ++nt)
            #pragma unroll
            for (int reg = 0; reg < 4; ++reg) {
                int row = mBase + mt * 16 + quad * 4 + reg;
                int bb = row >> 11, ss = row & 2047;
                int h = nt * 16 + lan;
                unsigned short vb = f2bf(acc[mt][nt][reg] * scale);
                if (z < 2) dst[((size_t)(bb * NH_ + head) * SS_ + ss) * 64 + h] = vb;
                else       dst[((size_t)(bb * NH_ + head) * 64 + h) * SS_ + ss] = vb;
            }
}

// ---------- K2: flash attention, LDS-staged K/V, XCD-swizzled ----------
// grid: 512 flat blocks x 128 threads (2 waves). Block f:
//   bn = (f&7) | ((f>>3)&3)<<3   (all blocks of bn on XCD bn%8)
//   p  = f>>5; halves process chunks p and 31-p (64 q-rows each) -> 33 iters.
// K/V 64x64 tiles staged to LDS with per-row xor-swizzled 16B granules:
//   granule g of row r lives at slot g^(r&7)  (conflict-free frag reads).
__global__ __launch_bounds__(128) void flash_mfma_kernel(
    const unsigned short* __restrict__ q,
    const unsigned short* __restrict__ k,
    const unsigned short* __restrict__ vT,
    unsigned short* __restrict__ attn)
{
    __shared__ unsigned short ldsK[2][64 * 64];
    __shared__ unsigned short ldsV[2][64 * 64];
    const int l = threadIdx.x & 63, w = threadIdx.x >> 6;   // w: 0..1
    const int quad = l >> 4, lan = l & 15;
    const int f = blockIdx.x;
    const int bn = (f & 7) | (((f >> 3) & 3) << 3);
    const int p = f >> 5;                                   // 0..15

    const unsigned short* Qg = q  + (size_t)bn * SS_ * 64;
    const unsigned short* Kg = k  + (size_t)bn * SS_ * 64;
    const unsigned short* Vg = vT + (size_t)bn * 64 * SS_;

    // per-lane static staging pattern: lane covers row rl=l>>3, slot l&7,
    // which must hold source granule (l&7)^rl
    const int srl = l >> 3;
    const int sgx = (l & 7) ^ srl;

    #pragma unroll
    for (int half = 0; half < 2; ++half) {
        const int chunk = (half == 0) ? p : 31 - p;         // 0..31
        const int qRow0 = chunk * 64 + w * 32;

        bf16x8 Qf[2][2];
        #pragma unroll
        for (int s = 0; s < 2; ++s) {
            const unsigned short* Qr = Qg + (size_t)(qRow0 + s * 16 + lan) * 64 + quad * 8;
            Qf[s][0] = *(const bf16x8*)(Qr);
            Qf[s][1] = *(const bf16x8*)(Qr + 32);
        }

        float mrow[2] = {-INFINITY, -INFINITY}, lrow[2] = {0.f, 0.f};
        floatx4 o[4][2];
        #pragma unroll
        for (int t = 0; t < 4; ++t)
            #pragma unroll
            for (int s = 0; s < 2; ++s)
                #pragma unroll
                for (int i = 0; i < 4; ++i) o[t][s][i] = 0.f;

        __syncthreads();   // previous half's LDS readers done
        // prologue: stage kt=0 into buf 0 (each wave stages its 32 rows)
        #pragma unroll
        for (int i = 0; i < 4; ++i) {
            const int row = w * 32 + i * 8;
            gl_lds16(Kg + (size_t)(row + srl) * 64 + sgx * 8, &ldsK[0][row * 64]);
            gl_lds16(Vg + (size_t)(row + srl) * SS_ + sgx * 8, &ldsV[0][row * 64]);
        }

        for (int kt = 0; kt <= chunk; ++kt) {
            const int kBase = kt * 64;
            const int buf = kt & 1;
            __syncthreads();   // staging of kt visible; prev compute done
            if (kt < chunk) {  // stage kt+1 into the other buffer
                const int kB1 = kBase + 64;
                #pragma unroll
                for (int i = 0; i < 4; ++i) {
                    const int row = w * 32 + i * 8;
                    gl_lds16(Kg + (size_t)(kB1 + row + srl) * 64 + sgx * 8,
                             &ldsK[buf ^ 1][row * 64]);
                    gl_lds16(Vg + (size_t)(row + srl) * SS_ + kB1 + sgx * 8,
                             &ldsV[buf ^ 1][row * 64]);
                }
            }
            const unsigned short* Kb = &ldsK[buf][0];
            const unsigned short* Vb = &ldsV[buf][0];

            // S^T = K . Q^T
            floatx4 sc[4][2];
            #pragma unroll
            for (int nt = 0; nt < 4; ++nt) {
                const unsigned short* kr = Kb + (nt * 16 + lan) * 64;
                bf16x8 K0 = *(const bf16x8*)(kr + ((quad ^ (lan & 7)) << 3));
                bf16x8 K1 = *(const bf16x8*)(kr + (((quad + 4) ^ (lan & 7)) << 3));
                #pragma unroll
                for (int s = 0; s < 2; ++s) {
                    floatx4 zz; zz[0] = zz[1] = zz[2] = zz[3] = 0.f;
                    sc[nt][s] = __builtin_amdgcn_mfma_f32_16x16x32_bf16(K0, Qf[s][0], zz, 0, 0, 0);
                    sc[nt][s] = __builtin_amdgcn_mfma_f32_16x16x32_bf16(K1, Qf[s][1], sc[nt][s], 0, 0, 0);
                }
            }
            if (kt == chunk) {   // diagonal: mask k > q
                #pragma unroll
                for (int nt = 0; nt < 4; ++nt)
                    #pragma unroll
                    for (int s = 0; s < 2; ++s)
                        #pragma unroll
                        for (int reg = 0; reg < 4; ++reg)
                            if (kBase + nt * 16 + quad * 4 + reg > qRow0 + s * 16 + lan)
                                sc[nt][s][reg] = -INFINITY;
            }
            // per-lane online softmax (q-col = lan, per qsub)
            bf16x4 pb[4][2];
            #pragma unroll
            for (int s = 0; s < 2; ++s) {
                float mx = sc[0][s][0];
                #pragma unroll
                for (int nt = 0; nt < 4; ++nt)
                    #pragma unroll
                    for (int reg = 0; reg < 4; ++reg) mx = fmaxf(mx, sc[nt][s][reg]);
                mx = fmaxf(mx, __shfl_xor(mx, 16, 64));
                mx = fmaxf(mx, __shfl_xor(mx, 32, 64));
                const float mnew = fmaxf(mrow[s], mx);
                const float alpha = exp2f(mrow[s] - mnew);
                float sum = 0.f;
                #pragma unroll
                for (int nt = 0; nt < 4; ++nt)
                    #pragma unroll
                    for (int reg = 0; reg < 4; ++reg) {
                        float pp = exp2f(sc[nt][s][reg] - mnew);
                        sum += pp;
                        pb[nt][s][reg] = f2bf16(pp);
                    }
                sum += __shfl_xor(sum, 16, 64);
                sum += __shfl_xor(sum, 32, 64);
                lrow[s] = lrow[s] * alpha + sum;
                mrow[s] = mnew;
                #pragma unroll
                for (int t = 0; t < 4; ++t)
                    #pragma unroll
                    for (int i = 0; i < 4; ++i) o[t][s][i] *= alpha;
            }
            // O^T += V^T . P^T  (x16 MFMAs, V frags from swizzled LDS)
            #pragma unroll
            for (int t = 0; t < 4; ++t) {
                const unsigned short* vr = Vb + (t * 16 + lan) * 64 + ((quad & 1) << 2);
                #pragma unroll
                for (int nt = 0; nt < 4; ++nt) {
                    const int g = nt * 2 + (quad >> 1);
                    bf16x4 Vf = *(const bf16x4*)(vr + ((g ^ (lan & 7)) << 3));
                    #pragma unroll
                    for (int s = 0; s < 2; ++s)
                        o[t][s] = mfma_pv(Vf, pb[nt][s], o[t][s]);
                }
            }
        }
        #pragma unroll
        for (int s = 0; s < 2; ++s) {
            const float rl = 1.f / lrow[s];
            const int qAbs = qRow0 + s * 16 + lan;
            #pragma unroll
            for (int t = 0; t < 4; ++t) {
                bf16x4 ob;
                #pragma unroll
                for (int reg = 0; reg < 4; ++reg) ob[reg] = f2bf16(o[t][s][reg] * rl);
                *(bf16x4*)(attn + ((size_t)bn * SS_ + qAbs) * 64 + t * 16 + quad * 4) = ob;
            }
        }
    }
}

// ---------- K3: output projection, zero-LDS MFMA ----------
__global__ __launch_bounds__(256) void out_mfma_kernel(
    const unsigned short* __restrict__ attn,
    const unsigned short* __restrict__ WOt,
    float* __restrict__ out)
{
    const int l = threadIdx.x & 63, w = threadIdx.x >> 6;
    const int quad = l >> 4, lan = l & 15;
    const int mBase = blockIdx.x * 128 + w * 32;
    const int nBase = blockIdx.y * 64;

    floatx4 acc[2][4];
    #pragma unroll
    for (int a = 0; a < 2; ++a)
        #pragma unroll
        for (int b = 0; b < 4; ++b)
            #pragma unroll
            for (int i = 0; i < 4; ++i) acc[a][b][i] = 0.f;

    const int row0 = mBase + lan, row1 = row0 + 16;
    const int bb0 = row0 >> 11, ss0 = row0 & 2047;
    const int bb1 = row1 >> 11, ss1 = row1 & 2047;
    const unsigned short* Brow = WOt + (size_t)(nBase + lan) * DD_ + quad * 8;

    #pragma unroll 2
    for (int k0 = 0; k0 < DD_; k0 += 32) {
        const int head = k0 >> 6, hh = (k0 & 63) + quad * 8;
        bf16x8 A0 = *(const bf16x8*)(attn + ((size_t)(bb0 * NH_ + head) * SS_ + ss0) * 64 + hh);
        bf16x8 A1 = *(const bf16x8*)(attn + ((size_t)(bb1 * NH_ + head) * SS_ + ss1) * 64 + hh);
        bf16x8 B0 = *(const bf16x8*)(Brow + k0);
        bf16x8 B1 = *(const bf16x8*)(Brow + 16 * DD_ + k0);
        bf16x8 B2 = *(const bf16x8*)(Brow + 32 * DD_ + k0);
        bf16x8 B3 = *(const bf16x8*)(Brow + 48 * DD_ + k0);
        acc[0][0] = __builtin_amdgcn_mfma_f32_16x16x32_bf16(A0, B0, acc[0][0], 0, 0, 0);
        acc[0][1] = __builtin_amdgcn_mfma_f32_16x16x32_bf16(A0, B1, acc[0][1], 0, 0, 0);
        acc[0][2] = __builtin_amdgcn_mfma_f32_16x16x32_bf16(A0, B2, acc[0][2], 0, 0, 0);
        acc[0][3] = __builtin_amdgcn_mfma_f32_16x16x32_bf16(A0, B3, acc[0][3], 0, 0, 0);
        acc[1][0] = __builtin_amdgcn_mfma_f32_16x16x32_bf16(A1, B0, acc[1][0], 0, 0, 0);
        acc[1][1] = __builtin_amdgcn_mfma_f32_16x16x32_bf16(A1, B1, acc[1][1], 0, 0, 0);
        acc[1][2] = __builtin_amdgcn_mfma_f32_16x16x32_bf16(A1, B2, acc[1][2], 0, 0, 0);
        acc[1][3] = __builtin_amdgcn_mfma_f32_16x16x32_bf16(A1, B3, acc[1][3], 0, 0, 0);
    }
    #pragma unroll
    for (int mt = 0; mt < 2; ++mt)
        #pragma unroll
        for (int nt = 0; nt < 4; ++nt)
            #pragma unroll
            for (int reg = 0; reg < 4; ++reg) {
                int row = mBase + mt * 16 + quad * 4 + reg;
                out[(size_t)row * DD_ + nBase + nt * 16 + lan] = acc[mt][nt][reg];
            }
}

extern "C" void kernel_launch(void* const* d_in, const int* in_sizes, int n_in,
                              void* d_out, int out_size, void* d_ws, size_t ws_size,
                              hipStream_t stream) {
    const float* resid = (const float*)d_in[0];
    const float* WQ    = (const float*)d_in[1];
    const float* WK    = (const float*)d_in[2];
    const float* WV    = (const float*)d_in[3];
    const float* WO    = (const float*)d_in[4];
    float* out = (float*)d_out;

    unsigned short* q      = (unsigned short*)d_ws;
    unsigned short* kk     = q      + 4194304;
    unsigned short* vT     = kk     + 4194304;
    unsigned short* attn   = vT     + 4194304;
    unsigned short* residB = attn   + 4194304;
    unsigned short* WQb    = residB + 4194304;
    unsigned short* WKb    = WQb    + 1048576;
    unsigned short* WVb    = WKb    + 1048576;
    unsigned short* WOt    = WVb    + 1048576;

    cast_bf16_kernel<<<dim3(4096, 4), 256, 0, stream>>>(
        resid, WQ, WK, WV, residB, WQb, WKb, WVb);
    wo_transpose_kernel<<<dim3(16, 16), 256, 0, stream>>>(WO, WOt);
    qkv_mfma_kernel<<<dim3(32, 16, 3), 256, 0, stream>>>(
        residB, WQb, WKb, WVb, q, kk, vT);
    flash_mfma_kernel<<<dim3(512), dim3(128), 0, stream>>>(q, kk, vT, attn);
    out_mfma_kernel<<<dim3(32, 16), 256, 0, stream>>>(attn, WOt, out);
}

// Round 6
// 257.757 us; speedup vs baseline: 7.2305x; 1.3726x over previous
//
#include <hip/hip_runtime.h>
#include <math.h>

// R6: qkv + out projections rewritten m97-style (128x128 tile, BK=64,
// global_load_lds width=16 staging, 2-barrier K-loop, 4x4 16x16x32 MFMA
// sub-tiles per wave). Flash kernel unchanged from R5 (verified).
// Layouts (verified R2-R5, absmax 7.8e-3):
//   x32 A-frag: m=lane&15, k=(lane>>4)*8+j ; B-frag: n=lane&15, k=(lane>>4)*8+j
//   x16 A/B-frag: idx=lane&15, k=(lane>>4)*4+j
//   C/D (all 16x16): col=lane&15, row=(lane>>4)*4+reg

#define SS_ 2048
#define DD_ 1024
#define NH_ 16
#define BN_ 32
#define BS_ 4096

typedef __bf16 bf16x8 __attribute__((ext_vector_type(8)));
typedef __bf16 bf16x4 __attribute__((ext_vector_type(4)));
typedef short shortx4 __attribute__((ext_vector_type(4)));
typedef float floatx4 __attribute__((ext_vector_type(4)));
typedef unsigned short ushortx4 __attribute__((ext_vector_type(4)));

__device__ __forceinline__ unsigned short f2bf(float f) {
    union { float f; unsigned u; } v; v.f = f;
    unsigned r = v.u + 0x7FFFu + ((v.u >> 16) & 1u);   // RNE
    return (unsigned short)(r >> 16);
}
__device__ __forceinline__ __bf16 f2bf16(float f) {
    unsigned short u = f2bf(f);
    return __builtin_bit_cast(__bf16, u);
}

__device__ __forceinline__ floatx4 mfma_pv(bf16x4 a, bf16x4 b, floatx4 c) {
#if __has_builtin(__builtin_amdgcn_mfma_f32_16x16x16_bf16)
    return __builtin_amdgcn_mfma_f32_16x16x16_bf16(a, b, c, 0, 0, 0);
#else
    return __builtin_amdgcn_mfma_f32_16x16x16bf16_1k(
        __builtin_bit_cast(shortx4, a), __builtin_bit_cast(shortx4, b), c, 0, 0, 0);
#endif
}

__device__ __forceinline__ void gl_lds16(const unsigned short* g, unsigned short* l) {
    __builtin_amdgcn_global_load_lds(
        (const __attribute__((address_space(1))) unsigned int*)g,
        (__attribute__((address_space(3))) unsigned int*)l, 16, 0, 0);
}

// ---------- K0a: cast resid + WQ/WK/WV to bf16 ----------
__global__ __launch_bounds__(256) void cast_bf16_kernel(
    const float* __restrict__ resid, const float* __restrict__ WQ,
    const float* __restrict__ WK, const float* __restrict__ WV,
    unsigned short* __restrict__ residB, unsigned short* __restrict__ WQb,
    unsigned short* __restrict__ WKb, unsigned short* __restrict__ WVb)
{
    const int z = blockIdx.y;
    if (z > 0 && blockIdx.x >= 1024) return;
    const float* src = (z == 0) ? resid : (z == 1) ? WQ : (z == 2) ? WK : WV;
    unsigned short* dst = (z == 0) ? residB : (z == 1) ? WQb : (z == 2) ? WKb : WVb;
    const int i = (blockIdx.x * 256 + threadIdx.x) * 4;
    float4 f = *(const float4*)(src + i);
    ushortx4 o;
    o[0] = f2bf(f.x); o[1] = f2bf(f.y); o[2] = f2bf(f.z); o[3] = f2bf(f.w);
    *(ushortx4*)(dst + i) = o;
}

// ---------- K0b: WO [kk=n*64+h][d] fp32 -> WOt [d][kk] bf16 ----------
__global__ __launch_bounds__(256) void wo_transpose_kernel(
    const float* __restrict__ WO, unsigned short* __restrict__ WOt)
{
    __shared__ float t[64][65];
    const int kk0 = blockIdx.x * 64, d0 = blockIdx.y * 64;
    #pragma unroll
    for (int it = 0; it < 16; ++it) {
        int idx = it * 256 + threadIdx.x;
        int r = idx >> 6, c = idx & 63;
        t[r][c] = WO[(kk0 + r) * DD_ + d0 + c];
    }
    __syncthreads();
    #pragma unroll
    for (int it = 0; it < 16; ++it) {
        int idx = it * 256 + threadIdx.x;
        int r = idx >> 6, c = idx & 63;
        WOt[(d0 + r) * DD_ + kk0 + c] = f2bf(t[c][r]);
    }
}

// ---------- K1: QKV projections, m97-style LDS-staged GEMM ----------
// C[m][n] = sum_d resid[m,d]*W[n,d]; 128x128 tile, BK=64.
__global__ __launch_bounds__(256) void qkv_m97_kernel(
    const unsigned short* __restrict__ residB,
    const unsigned short* __restrict__ WQb,
    const unsigned short* __restrict__ WKb,
    const unsigned short* __restrict__ WVb,
    unsigned short* __restrict__ q, unsigned short* __restrict__ kk,
    unsigned short* __restrict__ vT)
{
    __shared__ unsigned short As[128 * 64];
    __shared__ unsigned short Bs[128 * 64];
    const int tid = threadIdx.x;
    const int l = tid & 63, w = tid >> 6;
    const int quad = l >> 4, lan = l & 15;
    const int z = blockIdx.z;
    const unsigned short* W = (z == 0) ? WQb : (z == 1) ? WKb : WVb;
    unsigned short* dst = (z == 0) ? q : (z == 1) ? kk : vT;
    const int mBase = blockIdx.x * 128;
    const int nBase = blockIdx.y * 128;
    const int wm = (w & 1) * 64, wn = (w >> 1) * 64;

    floatx4 acc[4][4];
    #pragma unroll
    for (int a = 0; a < 4; ++a)
        #pragma unroll
        for (int b = 0; b < 4; ++b)
            #pragma unroll
            for (int i = 0; i < 4; ++i) acc[a][b][i] = 0.f;

    const int srow = tid >> 3, sg = (tid & 7) * 8;   // staging: row/granule per thread

    for (int k0 = 0; k0 < DD_; k0 += 64) {
        __syncthreads();   // previous iteration's LDS readers done
        #pragma unroll
        for (int i = 0; i < 4; ++i) {
            gl_lds16(residB + (size_t)(mBase + i * 32 + srow) * DD_ + k0 + sg,
                     As + i * 2048 + w * 512);
            gl_lds16(W + (size_t)(nBase + i * 32 + srow) * DD_ + k0 + sg,
                     Bs + i * 2048 + w * 512);
        }
        __syncthreads();   // staging visible (compiler drains vmcnt)
        #pragma unroll
        for (int ks = 0; ks < 2; ++ks) {
            bf16x8 a[4], b[4];
            #pragma unroll
            for (int mi = 0; mi < 4; ++mi)
                a[mi] = *(const bf16x8*)(As + (wm + mi * 16 + lan) * 64 + ks * 32 + quad * 8);
            #pragma unroll
            for (int ni = 0; ni < 4; ++ni)
                b[ni] = *(const bf16x8*)(Bs + (wn + ni * 16 + lan) * 64 + ks * 32 + quad * 8);
            #pragma unroll
            for (int mi = 0; mi < 4; ++mi)
                #pragma unroll
                for (int ni = 0; ni < 4; ++ni)
                    acc[mi][ni] = __builtin_amdgcn_mfma_f32_16x16x32_bf16(
                        a[mi], b[ni], acc[mi][ni], 0, 0, 0);
        }
    }
    // epilogue: n-range [nBase+wn, +64) is one head (uniform per wave)
    const int headU = (nBase + wn) >> 6;
    const float scale = (z == 0) ? 0.125f * 1.44269504088896340736f : 1.0f;
    #pragma unroll
    for (int mi = 0; mi < 4; ++mi)
        #pragma unroll
        for (int ni = 0; ni < 4; ++ni)
            #pragma unroll
            for (int reg = 0; reg < 4; ++reg) {
                int m = mBase + wm + mi * 16 + quad * 4 + reg;
                int bb = m >> 11, ss = m & 2047;
                int h = ni * 16 + lan;
                unsigned short vb = f2bf(acc[mi][ni][reg] * scale);
                if (z < 2) dst[((size_t)(bb * NH_ + headU) * SS_ + ss) * 64 + h] = vb;
                else       dst[((size_t)(bb * NH_ + headU) * 64 + h) * SS_ + ss] = vb;
            }
}

// ---------- K2: flash attention, LDS-staged K/V, XCD-swizzled (R5) ----------
__global__ __launch_bounds__(128) void flash_mfma_kernel(
    const unsigned short* __restrict__ q,
    const unsigned short* __restrict__ k,
    const unsigned short* __restrict__ vT,
    unsigned short* __restrict__ attn)
{
    __shared__ unsigned short ldsK[2][64 * 64];
    __shared__ unsigned short ldsV[2][64 * 64];
    const int l = threadIdx.x & 63, w = threadIdx.x >> 6;   // w: 0..1
    const int quad = l >> 4, lan = l & 15;
    const int f = blockIdx.x;
    const int bn = (f & 7) | (((f >> 3) & 3) << 3);
    const int p = f >> 5;                                   // 0..15

    const unsigned short* Qg = q  + (size_t)bn * SS_ * 64;
    const unsigned short* Kg = k  + (size_t)bn * SS_ * 64;
    const unsigned short* Vg = vT + (size_t)bn * 64 * SS_;

    const int srl = l >> 3;
    const int sgx = (l & 7) ^ srl;

    #pragma unroll
    for (int half = 0; half < 2; ++half) {
        const int chunk = (half == 0) ? p : 31 - p;         // 0..31
        const int qRow0 = chunk * 64 + w * 32;

        bf16x8 Qf[2][2];
        #pragma unroll
        for (int s = 0; s < 2; ++s) {
            const unsigned short* Qr = Qg + (size_t)(qRow0 + s * 16 + lan) * 64 + quad * 8;
            Qf[s][0] = *(const bf16x8*)(Qr);
            Qf[s][1] = *(const bf16x8*)(Qr + 32);
        }

        float mrow[2] = {-INFINITY, -INFINITY}, lrow[2] = {0.f, 0.f};
        floatx4 o[4][2];
        #pragma unroll
        for (int t = 0; t < 4; ++t)
            #pragma unroll
            for (int s = 0; s < 2; ++s)
                #pragma unroll
                for (int i = 0; i < 4; ++i) o[t][s][i] = 0.f;

        __syncthreads();
        #pragma unroll
        for (int i = 0; i < 4; ++i) {
            const int row = w * 32 + i * 8;
            gl_lds16(Kg + (size_t)(row + srl) * 64 + sgx * 8, &ldsK[0][row * 64]);
            gl_lds16(Vg + (size_t)(row + srl) * SS_ + sgx * 8, &ldsV[0][row * 64]);
        }

        for (int kt = 0; kt <= chunk; ++kt) {
            const int kBase = kt * 64;
            const int buf = kt & 1;
            __syncthreads();
            if (kt < chunk) {
                const int kB1 = kBase + 64;
                #pragma unroll
                for (int i = 0; i < 4; ++i) {
                    const int row = w * 32 + i * 8;
                    gl_lds16(Kg + (size_t)(kB1 + row + srl) * 64 + sgx * 8,
                             &ldsK[buf ^ 1][row * 64]);
                    gl_lds16(Vg + (size_t)(row + srl) * SS_ + kB1 + sgx * 8,
                             &ldsV[buf ^ 1][row * 64]);
                }
            }
            const unsigned short* Kb = &ldsK[buf][0];
            const unsigned short* Vb = &ldsV[buf][0];

            floatx4 sc[4][2];
            #pragma unroll
            for (int nt = 0; nt < 4; ++nt) {
                const unsigned short* kr = Kb + (nt * 16 + lan) * 64;
                bf16x8 K0 = *(const bf16x8*)(kr + ((quad ^ (lan & 7)) << 3));
                bf16x8 K1 = *(const bf16x8*)(kr + (((quad + 4) ^ (lan & 7)) << 3));
                #pragma unroll
                for (int s = 0; s < 2; ++s) {
                    floatx4 zz; zz[0] = zz[1] = zz[2] = zz[3] = 0.f;
                    sc[nt][s] = __builtin_amdgcn_mfma_f32_16x16x32_bf16(K0, Qf[s][0], zz, 0, 0, 0);
                    sc[nt][s] = __builtin_amdgcn_mfma_f32_16x16x32_bf16(K1, Qf[s][1], sc[nt][s], 0, 0, 0);
                }
            }
            if (kt == chunk) {
                #pragma unroll
                for (int nt = 0; nt < 4; ++nt)
                    #pragma unroll
                    for (int s = 0; s < 2; ++s)
                        #pragma unroll
                        for (int reg = 0; reg < 4; ++reg)
                            if (kBase + nt * 16 + quad * 4 + reg > qRow0 + s * 16 + lan)
                                sc[nt][s][reg] = -INFINITY;
            }
            bf16x4 pb[4][2];
            #pragma unroll
            for (int s = 0; s < 2; ++s) {
                float mx = sc[0][s][0];
                #pragma unroll
                for (int nt = 0; nt < 4; ++nt)
                    #pragma unroll
                    for (int reg = 0; reg < 4; ++reg) mx = fmaxf(mx, sc[nt][s][reg]);
                mx = fmaxf(mx, __shfl_xor(mx, 16, 64));
                mx = fmaxf(mx, __shfl_xor(mx, 32, 64));
                const float mnew = fmaxf(mrow[s], mx);
                const float alpha = exp2f(mrow[s] - mnew);
                float sum = 0.f;
                #pragma unroll
                for (int nt = 0; nt < 4; ++nt)
                    #pragma unroll
                    for (int reg = 0; reg < 4; ++reg) {
                        float pp = exp2f(sc[nt][s][reg] - mnew);
                        sum += pp;
                        pb[nt][s][reg] = f2bf16(pp);
                    }
                sum += __shfl_xor(sum, 16, 64);
                sum += __shfl_xor(sum, 32, 64);
                lrow[s] = lrow[s] * alpha + sum;
                mrow[s] = mnew;
                #pragma unroll
                for (int t = 0; t < 4; ++t)
                    #pragma unroll
                    for (int i = 0; i < 4; ++i) o[t][s][i] *= alpha;
            }
            #pragma unroll
            for (int t = 0; t < 4; ++t) {
                const unsigned short* vr = Vb + (t * 16 + lan) * 64 + ((quad & 1) << 2);
                #pragma unroll
                for (int nt = 0; nt < 4; ++nt) {
                    const int g = nt * 2 + (quad >> 1);
                    bf16x4 Vf = *(const bf16x4*)(vr + ((g ^ (lan & 7)) << 3));
                    #pragma unroll
                    for (int s = 0; s < 2; ++s)
                        o[t][s] = mfma_pv(Vf, pb[nt][s], o[t][s]);
                }
            }
        }
        #pragma unroll
        for (int s = 0; s < 2; ++s) {
            const float rl = 1.f / lrow[s];
            const int qAbs = qRow0 + s * 16 + lan;
            #pragma unroll
            for (int t = 0; t < 4; ++t) {
                bf16x4 ob;
                #pragma unroll
                for (int reg = 0; reg < 4; ++reg) ob[reg] = f2bf16(o[t][s][reg] * rl);
                *(bf16x4*)(attn + ((size_t)bn * SS_ + qAbs) * 64 + t * 16 + quad * 4) = ob;
            }
        }
    }
}

// ---------- K3: output projection, m97-style LDS-staged GEMM ----------
// out[m][n] = sum_kk attn_gathered[m][kk] * WOt[n][kk]; BK=64 == one head.
__global__ __launch_bounds__(256) void out_m97_kernel(
    const unsigned short* __restrict__ attn,
    const unsigned short* __restrict__ WOt,
    float* __restrict__ out)
{
    __shared__ unsigned short As[128 * 64];
    __shared__ unsigned short Bs[128 * 64];
    const int tid = threadIdx.x;
    const int l = tid & 63, w = tid >> 6;
    const int quad = l >> 4, lan = l & 15;
    const int mBase = blockIdx.x * 128;
    const int nBase = blockIdx.y * 128;
    const int wm = (w & 1) * 64, wn = (w >> 1) * 64;
    const int bbU = mBase >> 11;            // uniform: 128 | 2048
    const int ssBase = mBase & 2047;

    floatx4 acc[4][4];
    #pragma unroll
    for (int a = 0; a < 4; ++a)
        #pragma unroll
        for (int b = 0; b < 4; ++b)
            #pragma unroll
            for (int i = 0; i < 4; ++i) acc[a][b][i] = 0.f;

    const int srow = tid >> 3, sg = (tid & 7) * 8;

    for (int kt = 0; kt < 16; ++kt) {
        const int k0 = kt * 64;
        __syncthreads();
        #pragma unroll
        for (int i = 0; i < 4; ++i) {
            gl_lds16(attn + ((size_t)(bbU * NH_ + kt) * SS_ + ssBase + i * 32 + srow) * 64 + sg,
                     As + i * 2048 + w * 512);
            gl_lds16(WOt + (size_t)(nBase + i * 32 + srow) * DD_ + k0 + sg,
                     Bs + i * 2048 + w * 512);
        }
        __syncthreads();
        #pragma unroll
        for (int ks = 0; ks < 2; ++ks) {
            bf16x8 a[4], b[4];
            #pragma unroll
            for (int mi = 0; mi < 4; ++mi)
                a[mi] = *(const bf16x8*)(As + (wm + mi * 16 + lan) * 64 + ks * 32 + quad * 8);
            #pragma unroll
            for (int ni = 0; ni < 4; ++ni)
                b[ni] = *(const bf16x8*)(Bs + (wn + ni * 16 + lan) * 64 + ks * 32 + quad * 8);
            #pragma unroll
            for (int mi = 0; mi < 4; ++mi)
                #pragma unroll
                for (int ni = 0; ni < 4; ++ni)
                    acc[mi][ni] = __builtin_amdgcn_mfma_f32_16x16x32_bf16(
                        a[mi], b[ni], acc[mi][ni], 0, 0, 0);
        }
    }
    #pragma unroll
    for (int mi = 0; mi < 4; ++mi)
        #pragma unroll
        for (int ni = 0; ni < 4; ++ni)
            #pragma unroll
            for (int reg = 0; reg < 4; ++reg) {
                int m = mBase + wm + mi * 16 + quad * 4 + reg;
                out[(size_t)m * DD_ + nBase + wn + ni * 16 + lan] = acc[mi][ni][reg];
            }
}

extern "C" void kernel_launch(void* const* d_in, const int* in_sizes, int n_in,
                              void* d_out, int out_size, void* d_ws, size_t ws_size,
                              hipStream_t stream) {
    const float* resid = (const float*)d_in[0];
    const float* WQ    = (const float*)d_in[1];
    const float* WK    = (const float*)d_in[2];
    const float* WV    = (const float*)d_in[3];
    const float* WO    = (const float*)d_in[4];
    float* out = (float*)d_out;

    unsigned short* q      = (unsigned short*)d_ws;
    unsigned short* kk     = q      + 4194304;
    unsigned short* vT     = kk     + 4194304;
    unsigned short* attn   = vT     + 4194304;
    unsigned short* residB = attn   + 4194304;
    unsigned short* WQb    = residB + 4194304;
    unsigned short* WKb    = WQb    + 1048576;
    unsigned short* WVb    = WKb    + 1048576;
    unsigned short* WOt    = WVb    + 1048576;

    cast_bf16_kernel<<<dim3(4096, 4), 256, 0, stream>>>(
        resid, WQ, WK, WV, residB, WQb, WKb, WVb);
    wo_transpose_kernel<<<dim3(16, 16), 256, 0, stream>>>(WO, WOt);
    qkv_m97_kernel<<<dim3(32, 8, 3), 256, 0, stream>>>(
        residB, WQb, WKb, WVb, q, kk, vT);
    flash_mfma_kernel<<<dim3(512), dim3(128), 0, stream>>>(q, kk, vT, attn);
    out_m97_kernel<<<dim3(32, 8), 256, 0, stream>>>(attn, WOt, out);
}

// Round 7
// 226.032 us; speedup vs baseline: 8.2453x; 1.1404x over previous
//
#include <hip/hip_runtime.h>
#include <math.h>

// R7: flash rework — 4-wave blocks (16 q-rows/wave, 8 waves/CU vs 4),
// native v_cvt_pk_bf16_f32 casts in the hot loop (manual RNE f2bf was
// ~4 VALU ops x32/iter). GEMMs (m97-style, R6-verified) unchanged.
// Layouts (verified R2-R6, absmax 7.8e-3):
//   x32 A-frag: m=lane&15, k=(lane>>4)*8+j ; B-frag: n=lane&15, k=(lane>>4)*8+j
//   x16 A/B-frag: idx=lane&15, k=(lane>>4)*4+j
//   C/D (all 16x16): col=lane&15, row=(lane>>4)*4+reg

#define SS_ 2048
#define DD_ 1024
#define NH_ 16
#define BN_ 32
#define BS_ 4096

typedef __bf16 bf16x8 __attribute__((ext_vector_type(8)));
typedef __bf16 bf16x4 __attribute__((ext_vector_type(4)));
typedef short shortx4 __attribute__((ext_vector_type(4)));
typedef float floatx4 __attribute__((ext_vector_type(4)));
typedef unsigned short ushortx4 __attribute__((ext_vector_type(4)));

__device__ __forceinline__ unsigned short f2bf(float f) {
    union { float f; unsigned u; } v; v.f = f;
    unsigned r = v.u + 0x7FFFu + ((v.u >> 16) & 1u);   // RNE
    return (unsigned short)(r >> 16);
}
__device__ __forceinline__ __bf16 f2bf16(float f) {
    unsigned short u = f2bf(f);
    return __builtin_bit_cast(__bf16, u);
}

__device__ __forceinline__ floatx4 mfma_pv(bf16x4 a, bf16x4 b, floatx4 c) {
#if __has_builtin(__builtin_amdgcn_mfma_f32_16x16x16_bf16)
    return __builtin_amdgcn_mfma_f32_16x16x16_bf16(a, b, c, 0, 0, 0);
#else
    return __builtin_amdgcn_mfma_f32_16x16x16bf16_1k(
        __builtin_bit_cast(shortx4, a), __builtin_bit_cast(shortx4, b), c, 0, 0, 0);
#endif
}

__device__ __forceinline__ void gl_lds16(const unsigned short* g, unsigned short* l) {
    __builtin_amdgcn_global_load_lds(
        (const __attribute__((address_space(1))) unsigned int*)g,
        (__attribute__((address_space(3))) unsigned int*)l, 16, 0, 0);
}

// ---------- K0a: cast resid + WQ/WK/WV to bf16 ----------
__global__ __launch_bounds__(256) void cast_bf16_kernel(
    const float* __restrict__ resid, const float* __restrict__ WQ,
    const float* __restrict__ WK, const float* __restrict__ WV,
    unsigned short* __restrict__ residB, unsigned short* __restrict__ WQb,
    unsigned short* __restrict__ WKb, unsigned short* __restrict__ WVb)
{
    const int z = blockIdx.y;
    if (z > 0 && blockIdx.x >= 1024) return;
    const float* src = (z == 0) ? resid : (z == 1) ? WQ : (z == 2) ? WK : WV;
    unsigned short* dst = (z == 0) ? residB : (z == 1) ? WQb : (z == 2) ? WKb : WVb;
    const int i = (blockIdx.x * 256 + threadIdx.x) * 4;
    float4 f = *(const float4*)(src + i);
    ushortx4 o;
    o[0] = f2bf(f.x); o[1] = f2bf(f.y); o[2] = f2bf(f.z); o[3] = f2bf(f.w);
    *(ushortx4*)(dst + i) = o;
}

// ---------- K0b: WO [kk=n*64+h][d] fp32 -> WOt [d][kk] bf16 ----------
__global__ __launch_bounds__(256) void wo_transpose_kernel(
    const float* __restrict__ WO, unsigned short* __restrict__ WOt)
{
    __shared__ float t[64][65];
    const int kk0 = blockIdx.x * 64, d0 = blockIdx.y * 64;
    #pragma unroll
    for (int it = 0; it < 16; ++it) {
        int idx = it * 256 + threadIdx.x;
        int r = idx >> 6, c = idx & 63;
        t[r][c] = WO[(kk0 + r) * DD_ + d0 + c];
    }
    __syncthreads();
    #pragma unroll
    for (int it = 0; it < 16; ++it) {
        int idx = it * 256 + threadIdx.x;
        int r = idx >> 6, c = idx & 63;
        WOt[(d0 + r) * DD_ + kk0 + c] = f2bf(t[c][r]);
    }
}

// ---------- K1: QKV projections, m97-style LDS-staged GEMM ----------
__global__ __launch_bounds__(256) void qkv_m97_kernel(
    const unsigned short* __restrict__ residB,
    const unsigned short* __restrict__ WQb,
    const unsigned short* __restrict__ WKb,
    const unsigned short* __restrict__ WVb,
    unsigned short* __restrict__ q, unsigned short* __restrict__ kk,
    unsigned short* __restrict__ vT)
{
    __shared__ unsigned short As[128 * 64];
    __shared__ unsigned short Bs[128 * 64];
    const int tid = threadIdx.x;
    const int l = tid & 63, w = tid >> 6;
    const int quad = l >> 4, lan = l & 15;
    const int z = blockIdx.z;
    const unsigned short* W = (z == 0) ? WQb : (z == 1) ? WKb : WVb;
    unsigned short* dst = (z == 0) ? q : (z == 1) ? kk : vT;
    const int mBase = blockIdx.x * 128;
    const int nBase = blockIdx.y * 128;
    const int wm = (w & 1) * 64, wn = (w >> 1) * 64;

    floatx4 acc[4][4];
    #pragma unroll
    for (int a = 0; a < 4; ++a)
        #pragma unroll
        for (int b = 0; b < 4; ++b)
            #pragma unroll
            for (int i = 0; i < 4; ++i) acc[a][b][i] = 0.f;

    const int srow = tid >> 3, sg = (tid & 7) * 8;

    for (int k0 = 0; k0 < DD_; k0 += 64) {
        __syncthreads();
        #pragma unroll
        for (int i = 0; i < 4; ++i) {
            gl_lds16(residB + (size_t)(mBase + i * 32 + srow) * DD_ + k0 + sg,
                     As + i * 2048 + w * 512);
            gl_lds16(W + (size_t)(nBase + i * 32 + srow) * DD_ + k0 + sg,
                     Bs + i * 2048 + w * 512);
        }
        __syncthreads();
        #pragma unroll
        for (int ks = 0; ks < 2; ++ks) {
            bf16x8 a[4], b[4];
            #pragma unroll
            for (int mi = 0; mi < 4; ++mi)
                a[mi] = *(const bf16x8*)(As + (wm + mi * 16 + lan) * 64 + ks * 32 + quad * 8);
            #pragma unroll
            for (int ni = 0; ni < 4; ++ni)
                b[ni] = *(const bf16x8*)(Bs + (wn + ni * 16 + lan) * 64 + ks * 32 + quad * 8);
            #pragma unroll
            for (int mi = 0; mi < 4; ++mi)
                #pragma unroll
                for (int ni = 0; ni < 4; ++ni)
                    acc[mi][ni] = __builtin_amdgcn_mfma_f32_16x16x32_bf16(
                        a[mi], b[ni], acc[mi][ni], 0, 0, 0);
        }
    }
    const int headU = (nBase + wn) >> 6;
    const float scale = (z == 0) ? 0.125f * 1.44269504088896340736f : 1.0f;
    #pragma unroll
    for (int mi = 0; mi < 4; ++mi)
        #pragma unroll
        for (int ni = 0; ni < 4; ++ni)
            #pragma unroll
            for (int reg = 0; reg < 4; ++reg) {
                int m = mBase + wm + mi * 16 + quad * 4 + reg;
                int bb = m >> 11, ss = m & 2047;
                int h = ni * 16 + lan;
                unsigned short vb = f2bf(acc[mi][ni][reg] * scale);
                if (z < 2) dst[((size_t)(bb * NH_ + headU) * SS_ + ss) * 64 + h] = vb;
                else       dst[((size_t)(bb * NH_ + headU) * 64 + h) * SS_ + ss] = vb;
            }
}

// ---------- K2: flash attention, 4 waves x 16 q-rows, LDS K/V ----------
__global__ __launch_bounds__(256) void flash_mfma_kernel(
    const unsigned short* __restrict__ q,
    const unsigned short* __restrict__ k,
    const unsigned short* __restrict__ vT,
    unsigned short* __restrict__ attn)
{
    __shared__ unsigned short ldsK[2][64 * 64];
    __shared__ unsigned short ldsV[2][64 * 64];
    const int l = threadIdx.x & 63, w = threadIdx.x >> 6;   // w: 0..3
    const int quad = l >> 4, lan = l & 15;
    const int f = blockIdx.x;
    const int bn = (f & 7) | (((f >> 3) & 3) << 3);
    const int p = f >> 5;                                   // 0..15

    const unsigned short* Qg = q  + (size_t)bn * SS_ * 64;
    const unsigned short* Kg = k  + (size_t)bn * SS_ * 64;
    const unsigned short* Vg = vT + (size_t)bn * 64 * SS_;

    const int srl = l >> 3;
    const int sgx = (l & 7) ^ srl;

    #pragma unroll
    for (int half = 0; half < 2; ++half) {
        const int chunk = (half == 0) ? p : 31 - p;         // 0..31
        const int qRow0 = chunk * 64 + w * 16;
        const int qAbs = qRow0 + lan;

        const unsigned short* Qr = Qg + (size_t)qAbs * 64 + quad * 8;
        bf16x8 Qf0 = *(const bf16x8*)(Qr);
        bf16x8 Qf1 = *(const bf16x8*)(Qr + 32);

        float mrow = -INFINITY, lrow = 0.f;
        floatx4 o[4];
        #pragma unroll
        for (int t = 0; t < 4; ++t)
            #pragma unroll
            for (int i = 0; i < 4; ++i) o[t][i] = 0.f;

        __syncthreads();   // previous half's LDS readers done
        // prologue: stage kt=0 (each wave stages 16 rows of K and V)
        #pragma unroll
        for (int i = 0; i < 2; ++i) {
            const int row = w * 16 + i * 8;
            gl_lds16(Kg + (size_t)(row + srl) * 64 + sgx * 8, &ldsK[0][row * 64]);
            gl_lds16(Vg + (size_t)(row + srl) * SS_ + sgx * 8, &ldsV[0][row * 64]);
        }

        for (int kt = 0; kt <= chunk; ++kt) {
            const int kBase = kt * 64;
            const int buf = kt & 1;
            __syncthreads();
            if (kt < chunk) {
                const int kB1 = kBase + 64;
                #pragma unroll
                for (int i = 0; i < 2; ++i) {
                    const int row = w * 16 + i * 8;
                    gl_lds16(Kg + (size_t)(kB1 + row + srl) * 64 + sgx * 8,
                             &ldsK[buf ^ 1][row * 64]);
                    gl_lds16(Vg + (size_t)(row + srl) * SS_ + kB1 + sgx * 8,
                             &ldsV[buf ^ 1][row * 64]);
                }
            }
            const unsigned short* Kb = &ldsK[buf][0];
            const unsigned short* Vb = &ldsV[buf][0];

            // S^T = K . Q^T
            floatx4 sc[4];
            #pragma unroll
            for (int nt = 0; nt < 4; ++nt) {
                const unsigned short* kr = Kb + (nt * 16 + lan) * 64;
                bf16x8 K0 = *(const bf16x8*)(kr + ((quad ^ (lan & 7)) << 3));
                bf16x8 K1 = *(const bf16x8*)(kr + (((quad + 4) ^ (lan & 7)) << 3));
                floatx4 zz; zz[0] = zz[1] = zz[2] = zz[3] = 0.f;
                sc[nt] = __builtin_amdgcn_mfma_f32_16x16x32_bf16(K0, Qf0, zz, 0, 0, 0);
                sc[nt] = __builtin_amdgcn_mfma_f32_16x16x32_bf16(K1, Qf1, sc[nt], 0, 0, 0);
            }
            if (kt == chunk) {   // diagonal: mask k > q
                #pragma unroll
                for (int nt = 0; nt < 4; ++nt)
                    #pragma unroll
                    for (int reg = 0; reg < 4; ++reg)
                        if (kBase + nt * 16 + quad * 4 + reg > qAbs)
                            sc[nt][reg] = -INFINITY;
            }
            // per-lane online softmax (q-col = lan)
            float mx = sc[0][0];
            #pragma unroll
            for (int nt = 0; nt < 4; ++nt)
                #pragma unroll
                for (int reg = 0; reg < 4; ++reg) mx = fmaxf(mx, sc[nt][reg]);
            mx = fmaxf(mx, __shfl_xor(mx, 16, 64));
            mx = fmaxf(mx, __shfl_xor(mx, 32, 64));
            const float mnew = fmaxf(mrow, mx);
            const float alpha = exp2f(mrow - mnew);
            bf16x4 pb[4];
            float sum = 0.f;
            #pragma unroll
            for (int nt = 0; nt < 4; ++nt)
                #pragma unroll
                for (int reg = 0; reg < 4; ++reg) {
                    float pp = exp2f(sc[nt][reg] - mnew);
                    sum += pp;
                    pb[nt][reg] = static_cast<__bf16>(pp);   // v_cvt_pk_bf16_f32
                }
            sum += __shfl_xor(sum, 16, 64);
            sum += __shfl_xor(sum, 32, 64);
            lrow = lrow * alpha + sum;
            mrow = mnew;
            #pragma unroll
            for (int t = 0; t < 4; ++t)
                #pragma unroll
                for (int i = 0; i < 4; ++i) o[t][i] *= alpha;
            // O^T += V^T . P^T
            #pragma unroll
            for (int t = 0; t < 4; ++t) {
                const unsigned short* vr = Vb + (t * 16 + lan) * 64 + ((quad & 1) << 2);
                #pragma unroll
                for (int nt = 0; nt < 4; ++nt) {
                    const int g = nt * 2 + (quad >> 1);
                    bf16x4 Vf = *(const bf16x4*)(vr + ((g ^ (lan & 7)) << 3));
                    o[t] = mfma_pv(Vf, pb[nt], o[t]);
                }
            }
        }
        const float rl = 1.f / lrow;
        #pragma unroll
        for (int t = 0; t < 4; ++t) {
            bf16x4 ob;
            #pragma unroll
            for (int reg = 0; reg < 4; ++reg)
                ob[reg] = static_cast<__bf16>(o[t][reg] * rl);
            *(bf16x4*)(attn + ((size_t)bn * SS_ + qAbs) * 64 + t * 16 + quad * 4) = ob;
        }
    }
}

// ---------- K3: output projection, m97-style LDS-staged GEMM ----------
__global__ __launch_bounds__(256) void out_m97_kernel(
    const unsigned short* __restrict__ attn,
    const unsigned short* __restrict__ WOt,
    float* __restrict__ out)
{
    __shared__ unsigned short As[128 * 64];
    __shared__ unsigned short Bs[128 * 64];
    const int tid = threadIdx.x;
    const int l = tid & 63, w = tid >> 6;
    const int quad = l >> 4, lan = l & 15;
    const int mBase = blockIdx.x * 128;
    const int nBase = blockIdx.y * 128;
    const int wm = (w & 1) * 64, wn = (w >> 1) * 64;
    const int bbU = mBase >> 11;
    const int ssBase = mBase & 2047;

    floatx4 acc[4][4];
    #pragma unroll
    for (int a = 0; a < 4; ++a)
        #pragma unroll
        for (int b = 0; b < 4; ++b)
            #pragma unroll
            for (int i = 0; i < 4; ++i) acc[a][b][i] = 0.f;

    const int srow = tid >> 3, sg = (tid & 7) * 8;

    for (int kt = 0; kt < 16; ++kt) {
        const int k0 = kt * 64;
        __syncthreads();
        #pragma unroll
        for (int i = 0; i < 4; ++i) {
            gl_lds16(attn + ((size_t)(bbU * NH_ + kt) * SS_ + ssBase + i * 32 + srow) * 64 + sg,
                     As + i * 2048 + w * 512);
            gl_lds16(WOt + (size_t)(nBase + i * 32 + srow) * DD_ + k0 + sg,
                     Bs + i * 2048 + w * 512);
        }
        __syncthreads();
        #pragma unroll
        for (int ks = 0; ks < 2; ++ks) {
            bf16x8 a[4], b[4];
            #pragma unroll
            for (int mi = 0; mi < 4; ++mi)
                a[mi] = *(const bf16x8*)(As + (wm + mi * 16 + lan) * 64 + ks * 32 + quad * 8);
            #pragma unroll
            for (int ni = 0; ni < 4; ++ni)
                b[ni] = *(const bf16x8*)(Bs + (wn + ni * 16 + lan) * 64 + ks * 32 + quad * 8);
            #pragma unroll
            for (int mi = 0; mi < 4; ++mi)
                #pragma unroll
                for (int ni = 0; ni < 4; ++ni)
                    acc[mi][ni] = __builtin_amdgcn_mfma_f32_16x16x32_bf16(
                        a[mi], b[ni], acc[mi][ni], 0, 0, 0);
        }
    }
    #pragma unroll
    for (int mi = 0; mi < 4; ++mi)
        #pragma unroll
        for (int ni = 0; ni < 4; ++ni)
            #pragma unroll
            for (int reg = 0; reg < 4; ++reg) {
                int m = mBase + wm + mi * 16 + quad * 4 + reg;
                out[(size_t)m * DD_ + nBase + wn + ni * 16 + lan] = acc[mi][ni][reg];
            }
}

extern "C" void kernel_launch(void* const* d_in, const int* in_sizes, int n_in,
                              void* d_out, int out_size, void* d_ws, size_t ws_size,
                              hipStream_t stream) {
    const float* resid = (const float*)d_in[0];
    const float* WQ    = (const float*)d_in[1];
    const float* WK    = (const float*)d_in[2];
    const float* WV    = (const float*)d_in[3];
    const float* WO    = (const float*)d_in[4];
    float* out = (float*)d_out;

    unsigned short* q      = (unsigned short*)d_ws;
    unsigned short* kk     = q      + 4194304;
    unsigned short* vT     = kk     + 4194304;
    unsigned short* attn   = vT     + 4194304;
    unsigned short* residB = attn   + 4194304;
    unsigned short* WQb    = residB + 4194304;
    unsigned short* WKb    = WQb    + 1048576;
    unsigned short* WVb    = WKb    + 1048576;
    unsigned short* WOt    = WVb    + 1048576;

    cast_bf16_kernel<<<dim3(4096, 4), 256, 0, stream>>>(
        resid, WQ, WK, WV, residB, WQb, WKb, WVb);
    wo_transpose_kernel<<<dim3(16, 16), 256, 0, stream>>>(WO, WOt);
    qkv_m97_kernel<<<dim3(32, 8, 3), 256, 0, stream>>>(
        residB, WQb, WKb, WVb, q, kk, vT);
    flash_mfma_kernel<<<dim3(512), dim3(256), 0, stream>>>(q, kk, vT, attn);
    out_m97_kernel<<<dim3(32, 8), 256, 0, stream>>>(attn, WOt, out);
}

// Round 8
// 206.094 us; speedup vs baseline: 9.0430x; 1.0967x over previous
//
#include <hip/hip_runtime.h>
#include <math.h>

// R8: kill the 16-way LDS bank conflicts in both m97-style GEMMs
// (row stride was 128B = exactly 32 banks -> all rows alias; 9.4M
// SQ_LDS_BANK_CONFLICT). Fix: xor-swizzle 16B granules within each row
// (slot = g ^ (r&7)) in staging + frag reads — same pattern already
// verified in the flash kernel. Also: vT epilogue packs 4 regs into one
// 8B bf16x4 store (was 4x 2B scatter). Flash unchanged from R7.
// Layouts (verified R2-R7, absmax 7.8e-3):
//   x32 A-frag: m=lane&15, k=(lane>>4)*8+j ; B-frag: n=lane&15, k=(lane>>4)*8+j
//   x16 A/B-frag: idx=lane&15, k=(lane>>4)*4+j
//   C/D (all 16x16): col=lane&15, row=(lane>>4)*4+reg

#define SS_ 2048
#define DD_ 1024
#define NH_ 16
#define BN_ 32
#define BS_ 4096

typedef __bf16 bf16x8 __attribute__((ext_vector_type(8)));
typedef __bf16 bf16x4 __attribute__((ext_vector_type(4)));
typedef short shortx4 __attribute__((ext_vector_type(4)));
typedef float floatx4 __attribute__((ext_vector_type(4)));
typedef unsigned short ushortx4 __attribute__((ext_vector_type(4)));

__device__ __forceinline__ unsigned short f2bf(float f) {
    union { float f; unsigned u; } v; v.f = f;
    unsigned r = v.u + 0x7FFFu + ((v.u >> 16) & 1u);   // RNE
    return (unsigned short)(r >> 16);
}

__device__ __forceinline__ floatx4 mfma_pv(bf16x4 a, bf16x4 b, floatx4 c) {
#if __has_builtin(__builtin_amdgcn_mfma_f32_16x16x16_bf16)
    return __builtin_amdgcn_mfma_f32_16x16x16_bf16(a, b, c, 0, 0, 0);
#else
    return __builtin_amdgcn_mfma_f32_16x16x16bf16_1k(
        __builtin_bit_cast(shortx4, a), __builtin_bit_cast(shortx4, b), c, 0, 0, 0);
#endif
}

__device__ __forceinline__ void gl_lds16(const unsigned short* g, unsigned short* l) {
    __builtin_amdgcn_global_load_lds(
        (const __attribute__((address_space(1))) unsigned int*)g,
        (__attribute__((address_space(3))) unsigned int*)l, 16, 0, 0);
}

// ---------- K0a: cast resid + WQ/WK/WV to bf16 ----------
__global__ __launch_bounds__(256) void cast_bf16_kernel(
    const float* __restrict__ resid, const float* __restrict__ WQ,
    const float* __restrict__ WK, const float* __restrict__ WV,
    unsigned short* __restrict__ residB, unsigned short* __restrict__ WQb,
    unsigned short* __restrict__ WKb, unsigned short* __restrict__ WVb)
{
    const int z = blockIdx.y;
    if (z > 0 && blockIdx.x >= 1024) return;
    const float* src = (z == 0) ? resid : (z == 1) ? WQ : (z == 2) ? WK : WV;
    unsigned short* dst = (z == 0) ? residB : (z == 1) ? WQb : (z == 2) ? WKb : WVb;
    const int i = (blockIdx.x * 256 + threadIdx.x) * 4;
    float4 f = *(const float4*)(src + i);
    ushortx4 o;
    o[0] = f2bf(f.x); o[1] = f2bf(f.y); o[2] = f2bf(f.z); o[3] = f2bf(f.w);
    *(ushortx4*)(dst + i) = o;
}

// ---------- K0b: WO [kk=n*64+h][d] fp32 -> WOt [d][kk] bf16 ----------
__global__ __launch_bounds__(256) void wo_transpose_kernel(
    const float* __restrict__ WO, unsigned short* __restrict__ WOt)
{
    __shared__ float t[64][65];
    const int kk0 = blockIdx.x * 64, d0 = blockIdx.y * 64;
    #pragma unroll
    for (int it = 0; it < 16; ++it) {
        int idx = it * 256 + threadIdx.x;
        int r = idx >> 6, c = idx & 63;
        t[r][c] = WO[(kk0 + r) * DD_ + d0 + c];
    }
    __syncthreads();
    #pragma unroll
    for (int it = 0; it < 16; ++it) {
        int idx = it * 256 + threadIdx.x;
        int r = idx >> 6, c = idx & 63;
        WOt[(d0 + r) * DD_ + kk0 + c] = f2bf(t[c][r]);
    }
}

// ---------- K1: QKV projections, m97 GEMM with swizzled LDS ----------
__global__ __launch_bounds__(256) void qkv_m97_kernel(
    const unsigned short* __restrict__ residB,
    const unsigned short* __restrict__ WQb,
    const unsigned short* __restrict__ WKb,
    const unsigned short* __restrict__ WVb,
    unsigned short* __restrict__ q, unsigned short* __restrict__ kk,
    unsigned short* __restrict__ vT)
{
    __shared__ unsigned short As[128 * 64];
    __shared__ unsigned short Bs[128 * 64];
    const int tid = threadIdx.x;
    const int l = tid & 63, w = tid >> 6;
    const int quad = l >> 4, lan = l & 15;
    const int z = blockIdx.z;
    const unsigned short* W = (z == 0) ? WQb : (z == 1) ? WKb : WVb;
    unsigned short* dst = (z == 0) ? q : (z == 1) ? kk : vT;
    const int mBase = blockIdx.x * 128;
    const int nBase = blockIdx.y * 128;
    const int wm = (w & 1) * 64, wn = (w >> 1) * 64;

    floatx4 acc[4][4];
    #pragma unroll
    for (int a = 0; a < 4; ++a)
        #pragma unroll
        for (int b = 0; b < 4; ++b)
            #pragma unroll
            for (int i = 0; i < 4; ++i) acc[a][b][i] = 0.f;

    // staging: lane covers LDS row (i*32 + w*8 + (l>>3)), slot l&7;
    // with xor-swizzle that slot holds source granule (l&7)^(l>>3)
    const int sr = l >> 3;
    const int sgx = ((l & 7) ^ sr) * 8;
    const int sw = (l & 7) ^ (lan & 7);  // unused helper (kept out); see reads

    for (int k0 = 0; k0 < DD_; k0 += 64) {
        __syncthreads();
        #pragma unroll
        for (int i = 0; i < 4; ++i) {
            const int row = i * 32 + w * 8 + sr;
            gl_lds16(residB + (size_t)(mBase + row) * DD_ + k0 + sgx,
                     As + i * 2048 + w * 512);
            gl_lds16(W + (size_t)(nBase + row) * DD_ + k0 + sgx,
                     Bs + i * 2048 + w * 512);
        }
        __syncthreads();
        #pragma unroll
        for (int ks = 0; ks < 2; ++ks) {
            const int fo = (((ks * 4 + quad) ^ (lan & 7)) << 3);   // swizzled frag offset
            bf16x8 a[4], b[4];
            #pragma unroll
            for (int mi = 0; mi < 4; ++mi)
                a[mi] = *(const bf16x8*)(As + (wm + mi * 16 + lan) * 64 + fo);
            #pragma unroll
            for (int ni = 0; ni < 4; ++ni)
                b[ni] = *(const bf16x8*)(Bs + (wn + ni * 16 + lan) * 64 + fo);
            #pragma unroll
            for (int mi = 0; mi < 4; ++mi)
                #pragma unroll
                for (int ni = 0; ni < 4; ++ni)
                    acc[mi][ni] = __builtin_amdgcn_mfma_f32_16x16x32_bf16(
                        a[mi], b[ni], acc[mi][ni], 0, 0, 0);
        }
    }
    const int headU = (nBase + wn) >> 6;
    const float scale = (z == 0) ? 0.125f * 1.44269504088896340736f : 1.0f;
    if (z < 2) {
        #pragma unroll
        for (int mi = 0; mi < 4; ++mi)
            #pragma unroll
            for (int ni = 0; ni < 4; ++ni)
                #pragma unroll
                for (int reg = 0; reg < 4; ++reg) {
                    int m = mBase + wm + mi * 16 + quad * 4 + reg;
                    int bb = m >> 11, ss = m & 2047;
                    int h = ni * 16 + lan;
                    dst[((size_t)(bb * NH_ + headU) * SS_ + ss) * 64 + h] =
                        f2bf(acc[mi][ni][reg] * scale);
                }
    } else {
        // vT[h][s]: the 4 C-regs are contiguous in s -> one 8B store
        #pragma unroll
        for (int mi = 0; mi < 4; ++mi) {
            const int m0 = mBase + wm + mi * 16 + quad * 4;
            const int bb = m0 >> 11, ss0 = m0 & 2047;
            #pragma unroll
            for (int ni = 0; ni < 4; ++ni) {
                const int h = ni * 16 + lan;
                bf16x4 ob;
                #pragma unroll
                for (int reg = 0; reg < 4; ++reg)
                    ob[reg] = static_cast<__bf16>(acc[mi][ni][reg]);
                *(bf16x4*)(dst + ((size_t)(bb * NH_ + headU) * 64 + h) * SS_ + ss0) = ob;
            }
        }
    }
}

// ---------- K2: flash attention, 4 waves x 16 q-rows, LDS K/V (R7) ----------
__global__ __launch_bounds__(256) void flash_mfma_kernel(
    const unsigned short* __restrict__ q,
    const unsigned short* __restrict__ k,
    const unsigned short* __restrict__ vT,
    unsigned short* __restrict__ attn)
{
    __shared__ unsigned short ldsK[2][64 * 64];
    __shared__ unsigned short ldsV[2][64 * 64];
    const int l = threadIdx.x & 63, w = threadIdx.x >> 6;   // w: 0..3
    const int quad = l >> 4, lan = l & 15;
    const int f = blockIdx.x;
    const int bn = (f & 7) | (((f >> 3) & 3) << 3);
    const int p = f >> 5;                                   // 0..15

    const unsigned short* Qg = q  + (size_t)bn * SS_ * 64;
    const unsigned short* Kg = k  + (size_t)bn * SS_ * 64;
    const unsigned short* Vg = vT + (size_t)bn * 64 * SS_;

    const int srl = l >> 3;
    const int sgx = (l & 7) ^ srl;

    #pragma unroll
    for (int half = 0; half < 2; ++half) {
        const int chunk = (half == 0) ? p : 31 - p;         // 0..31
        const int qRow0 = chunk * 64 + w * 16;
        const int qAbs = qRow0 + lan;

        const unsigned short* Qr = Qg + (size_t)qAbs * 64 + quad * 8;
        bf16x8 Qf0 = *(const bf16x8*)(Qr);
        bf16x8 Qf1 = *(const bf16x8*)(Qr + 32);

        float mrow = -INFINITY, lrow = 0.f;
        floatx4 o[4];
        #pragma unroll
        for (int t = 0; t < 4; ++t)
            #pragma unroll
            for (int i = 0; i < 4; ++i) o[t][i] = 0.f;

        __syncthreads();
        #pragma unroll
        for (int i = 0; i < 2; ++i) {
            const int row = w * 16 + i * 8;
            gl_lds16(Kg + (size_t)(row + srl) * 64 + sgx * 8, &ldsK[0][row * 64]);
            gl_lds16(Vg + (size_t)(row + srl) * SS_ + sgx * 8, &ldsV[0][row * 64]);
        }

        for (int kt = 0; kt <= chunk; ++kt) {
            const int kBase = kt * 64;
            const int buf = kt & 1;
            __syncthreads();
            if (kt < chunk) {
                const int kB1 = kBase + 64;
                #pragma unroll
                for (int i = 0; i < 2; ++i) {
                    const int row = w * 16 + i * 8;
                    gl_lds16(Kg + (size_t)(kB1 + row + srl) * 64 + sgx * 8,
                             &ldsK[buf ^ 1][row * 64]);
                    gl_lds16(Vg + (size_t)(row + srl) * SS_ + kB1 + sgx * 8,
                             &ldsV[buf ^ 1][row * 64]);
                }
            }
            const unsigned short* Kb = &ldsK[buf][0];
            const unsigned short* Vb = &ldsV[buf][0];

            floatx4 sc[4];
            #pragma unroll
            for (int nt = 0; nt < 4; ++nt) {
                const unsigned short* kr = Kb + (nt * 16 + lan) * 64;
                bf16x8 K0 = *(const bf16x8*)(kr + ((quad ^ (lan & 7)) << 3));
                bf16x8 K1 = *(const bf16x8*)(kr + (((quad + 4) ^ (lan & 7)) << 3));
                floatx4 zz; zz[0] = zz[1] = zz[2] = zz[3] = 0.f;
                sc[nt] = __builtin_amdgcn_mfma_f32_16x16x32_bf16(K0, Qf0, zz, 0, 0, 0);
                sc[nt] = __builtin_amdgcn_mfma_f32_16x16x32_bf16(K1, Qf1, sc[nt], 0, 0, 0);
            }
            if (kt == chunk) {
                #pragma unroll
                for (int nt = 0; nt < 4; ++nt)
                    #pragma unroll
                    for (int reg = 0; reg < 4; ++reg)
                        if (kBase + nt * 16 + quad * 4 + reg > qAbs)
                            sc[nt][reg] = -INFINITY;
            }
            float mx = sc[0][0];
            #pragma unroll
            for (int nt = 0; nt < 4; ++nt)
                #pragma unroll
                for (int reg = 0; reg < 4; ++reg) mx = fmaxf(mx, sc[nt][reg]);
            mx = fmaxf(mx, __shfl_xor(mx, 16, 64));
            mx = fmaxf(mx, __shfl_xor(mx, 32, 64));
            const float mnew = fmaxf(mrow, mx);
            const float alpha = exp2f(mrow - mnew);
            bf16x4 pb[4];
            float sum = 0.f;
            #pragma unroll
            for (int nt = 0; nt < 4; ++nt)
                #pragma unroll
                for (int reg = 0; reg < 4; ++reg) {
                    float pp = exp2f(sc[nt][reg] - mnew);
                    sum += pp;
                    pb[nt][reg] = static_cast<__bf16>(pp);
                }
            sum += __shfl_xor(sum, 16, 64);
            sum += __shfl_xor(sum, 32, 64);
            lrow = lrow * alpha + sum;
            mrow = mnew;
            #pragma unroll
            for (int t = 0; t < 4; ++t)
                #pragma unroll
                for (int i = 0; i < 4; ++i) o[t][i] *= alpha;
            #pragma unroll
            for (int t = 0; t < 4; ++t) {
                const unsigned short* vr = Vb + (t * 16 + lan) * 64 + ((quad & 1) << 2);
                #pragma unroll
                for (int nt = 0; nt < 4; ++nt) {
                    const int g = nt * 2 + (quad >> 1);
                    bf16x4 Vf = *(const bf16x4*)(vr + ((g ^ (lan & 7)) << 3));
                    o[t] = mfma_pv(Vf, pb[nt], o[t]);
                }
            }
        }
        const float rl = 1.f / lrow;
        #pragma unroll
        for (int t = 0; t < 4; ++t) {
            bf16x4 ob;
            #pragma unroll
            for (int reg = 0; reg < 4; ++reg)
                ob[reg] = static_cast<__bf16>(o[t][reg] * rl);
            *(bf16x4*)(attn + ((size_t)bn * SS_ + qAbs) * 64 + t * 16 + quad * 4) = ob;
        }
    }
}

// ---------- K3: output projection, m97 GEMM with swizzled LDS ----------
__global__ __launch_bounds__(256) void out_m97_kernel(
    const unsigned short* __restrict__ attn,
    const unsigned short* __restrict__ WOt,
    float* __restrict__ out)
{
    __shared__ unsigned short As[128 * 64];
    __shared__ unsigned short Bs[128 * 64];
    const int tid = threadIdx.x;
    const int l = tid & 63, w = tid >> 6;
    const int quad = l >> 4, lan = l & 15;
    const int mBase = blockIdx.x * 128;
    const int nBase = blockIdx.y * 128;
    const int wm = (w & 1) * 64, wn = (w >> 1) * 64;
    const int bbU = mBase >> 11;
    const int ssBase = mBase & 2047;

    floatx4 acc[4][4];
    #pragma unroll
    for (int a = 0; a < 4; ++a)
        #pragma unroll
        for (int b = 0; b < 4; ++b)
            #pragma unroll
            for (int i = 0; i < 4; ++i) acc[a][b][i] = 0.f;

    const int sr = l >> 3;
    const int sgx = ((l & 7) ^ sr) * 8;

    for (int kt = 0; kt < 16; ++kt) {
        const int k0 = kt * 64;
        __syncthreads();
        #pragma unroll
        for (int i = 0; i < 4; ++i) {
            const int row = i * 32 + w * 8 + sr;
            gl_lds16(attn + ((size_t)(bbU * NH_ + kt) * SS_ + ssBase + row) * 64 + sgx,
                     As + i * 2048 + w * 512);
            gl_lds16(WOt + (size_t)(nBase + row) * DD_ + k0 + sgx,
                     Bs + i * 2048 + w * 512);
        }
        __syncthreads();
        #pragma unroll
        for (int ks = 0; ks < 2; ++ks) {
            const int fo = (((ks * 4 + quad) ^ (lan & 7)) << 3);
            bf16x8 a[4], b[4];
            #pragma unroll
            for (int mi = 0; mi < 4; ++mi)
                a[mi] = *(const bf16x8*)(As + (wm + mi * 16 + lan) * 64 + fo);
            #pragma unroll
            for (int ni = 0; ni < 4; ++ni)
                b[ni] = *(const bf16x8*)(Bs + (wn + ni * 16 + lan) * 64 + fo);
            #pragma unroll
            for (int mi = 0; mi < 4; ++mi)
                #pragma unroll
                for (int ni = 0; ni < 4; ++ni)
                    acc[mi][ni] = __builtin_amdgcn_mfma_f32_16x16x32_bf16(
                        a[mi], b[ni], acc[mi][ni], 0, 0, 0);
        }
    }
    #pragma unroll
    for (int mi = 0; mi < 4; ++mi)
        #pragma unroll
        for (int ni = 0; ni < 4; ++ni)
            #pragma unroll
            for (int reg = 0; reg < 4; ++reg) {
                int m = mBase + wm + mi * 16 + quad * 4 + reg;
                out[(size_t)m * DD_ + nBase + wn + ni * 16 + lan] = acc[mi][ni][reg];
            }
}

extern "C" void kernel_launch(void* const* d_in, const int* in_sizes, int n_in,
                              void* d_out, int out_size, void* d_ws, size_t ws_size,
                              hipStream_t stream) {
    const float* resid = (const float*)d_in[0];
    const float* WQ    = (const float*)d_in[1];
    const float* WK    = (const float*)d_in[2];
    const float* WV    = (const float*)d_in[3];
    const float* WO    = (const float*)d_in[4];
    float* out = (float*)d_out;

    unsigned short* q      = (unsigned short*)d_ws;
    unsigned short* kk     = q      + 4194304;
    unsigned short* vT     = kk     + 4194304;
    unsigned short* attn   = vT     + 4194304;
    unsigned short* residB = attn   + 4194304;
    unsigned short* WQb    = residB + 4194304;
    unsigned short* WKb    = WQb    + 1048576;
    unsigned short* WVb    = WKb    + 1048576;
    unsigned short* WOt    = WVb    + 1048576;

    cast_bf16_kernel<<<dim3(4096, 4), 256, 0, stream>>>(
        resid, WQ, WK, WV, residB, WQb, WKb, WVb);
    wo_transpose_kernel<<<dim3(16, 16), 256, 0, stream>>>(WO, WOt);
    qkv_m97_kernel<<<dim3(32, 8, 3), 256, 0, stream>>>(
        residB, WQb, WKb, WVb, q, kk, vT);
    flash_mfma_kernel<<<dim3(512), dim3(256), 0, stream>>>(q, kk, vT, attn);
    out_m97_kernel<<<dim3(32, 8), 256, 0, stream>>>(attn, WOt, out);
}

// Round 9
// 196.671 us; speedup vs baseline: 9.4762x; 1.0479x over previous
//
#include <hip/hip_runtime.h>
#include <math.h>

// R9: flash occupancy + softmax-pipe rebalance.
//  - grid 1024 blocks (one 64-row chunk each), heavy-first dispatch
//    (chunk = 31 - f>>5), XCD swizzle in low 5 bits -> 4 blocks/CU
//    (was 2), 16 waves/CU for latency hiding.
//  - l (softmax denominator) accumulated by 4 ones-column K=16 MFMAs
//    instead of 16 VALU adds + 2 ds_swizzle reductions per iter; only
//    l_acc[0] is alpha-rescaled. More consistent too (l sums the same
//    bf16-rounded P that PV consumes).
// GEMMs (m97 + xor-swizzled LDS, R8-verified) unchanged.
// Layouts (verified R2-R8, absmax 7.8e-3):
//   x32 A-frag: m=lane&15, k=(lane>>4)*8+j ; B-frag: n=lane&15, k=(lane>>4)*8+j
//   x16 A/B-frag: idx=lane&15, k=(lane>>4)*4+j
//   C/D (all 16x16): col=lane&15, row=(lane>>4)*4+reg

#define SS_ 2048
#define DD_ 1024
#define NH_ 16
#define BN_ 32
#define BS_ 4096

typedef __bf16 bf16x8 __attribute__((ext_vector_type(8)));
typedef __bf16 bf16x4 __attribute__((ext_vector_type(4)));
typedef short shortx4 __attribute__((ext_vector_type(4)));
typedef float floatx4 __attribute__((ext_vector_type(4)));
typedef unsigned short ushortx4 __attribute__((ext_vector_type(4)));

__device__ __forceinline__ unsigned short f2bf(float f) {
    union { float f; unsigned u; } v; v.f = f;
    unsigned r = v.u + 0x7FFFu + ((v.u >> 16) & 1u);   // RNE
    return (unsigned short)(r >> 16);
}

__device__ __forceinline__ floatx4 mfma_pv(bf16x4 a, bf16x4 b, floatx4 c) {
#if __has_builtin(__builtin_amdgcn_mfma_f32_16x16x16_bf16)
    return __builtin_amdgcn_mfma_f32_16x16x16_bf16(a, b, c, 0, 0, 0);
#else
    return __builtin_amdgcn_mfma_f32_16x16x16bf16_1k(
        __builtin_bit_cast(shortx4, a), __builtin_bit_cast(shortx4, b), c, 0, 0, 0);
#endif
}

__device__ __forceinline__ void gl_lds16(const unsigned short* g, unsigned short* l) {
    __builtin_amdgcn_global_load_lds(
        (const __attribute__((address_space(1))) unsigned int*)g,
        (__attribute__((address_space(3))) unsigned int*)l, 16, 0, 0);
}

// ---------- K0a: cast resid + WQ/WK/WV to bf16 ----------
__global__ __launch_bounds__(256) void cast_bf16_kernel(
    const float* __restrict__ resid, const float* __restrict__ WQ,
    const float* __restrict__ WK, const float* __restrict__ WV,
    unsigned short* __restrict__ residB, unsigned short* __restrict__ WQb,
    unsigned short* __restrict__ WKb, unsigned short* __restrict__ WVb)
{
    const int z = blockIdx.y;
    if (z > 0 && blockIdx.x >= 1024) return;
    const float* src = (z == 0) ? resid : (z == 1) ? WQ : (z == 2) ? WK : WV;
    unsigned short* dst = (z == 0) ? residB : (z == 1) ? WQb : (z == 2) ? WKb : WVb;
    const int i = (blockIdx.x * 256 + threadIdx.x) * 4;
    float4 f = *(const float4*)(src + i);
    ushortx4 o;
    o[0] = f2bf(f.x); o[1] = f2bf(f.y); o[2] = f2bf(f.z); o[3] = f2bf(f.w);
    *(ushortx4*)(dst + i) = o;
}

// ---------- K0b: WO [kk=n*64+h][d] fp32 -> WOt [d][kk] bf16 ----------
__global__ __launch_bounds__(256) void wo_transpose_kernel(
    const float* __restrict__ WO, unsigned short* __restrict__ WOt)
{
    __shared__ float t[64][65];
    const int kk0 = blockIdx.x * 64, d0 = blockIdx.y * 64;
    #pragma unroll
    for (int it = 0; it < 16; ++it) {
        int idx = it * 256 + threadIdx.x;
        int r = idx >> 6, c = idx & 63;
        t[r][c] = WO[(kk0 + r) * DD_ + d0 + c];
    }
    __syncthreads();
    #pragma unroll
    for (int it = 0; it < 16; ++it) {
        int idx = it * 256 + threadIdx.x;
        int r = idx >> 6, c = idx & 63;
        WOt[(d0 + r) * DD_ + kk0 + c] = f2bf(t[c][r]);
    }
}

// ---------- K1: QKV projections, m97 GEMM with swizzled LDS ----------
__global__ __launch_bounds__(256) void qkv_m97_kernel(
    const unsigned short* __restrict__ residB,
    const unsigned short* __restrict__ WQb,
    const unsigned short* __restrict__ WKb,
    const unsigned short* __restrict__ WVb,
    unsigned short* __restrict__ q, unsigned short* __restrict__ kk,
    unsigned short* __restrict__ vT)
{
    __shared__ unsigned short As[128 * 64];
    __shared__ unsigned short Bs[128 * 64];
    const int tid = threadIdx.x;
    const int l = tid & 63, w = tid >> 6;
    const int quad = l >> 4, lan = l & 15;
    const int z = blockIdx.z;
    const unsigned short* W = (z == 0) ? WQb : (z == 1) ? WKb : WVb;
    unsigned short* dst = (z == 0) ? q : (z == 1) ? kk : vT;
    const int mBase = blockIdx.x * 128;
    const int nBase = blockIdx.y * 128;
    const int wm = (w & 1) * 64, wn = (w >> 1) * 64;

    floatx4 acc[4][4];
    #pragma unroll
    for (int a = 0; a < 4; ++a)
        #pragma unroll
        for (int b = 0; b < 4; ++b)
            #pragma unroll
            for (int i = 0; i < 4; ++i) acc[a][b][i] = 0.f;

    const int sr = l >> 3;
    const int sgx = ((l & 7) ^ sr) * 8;

    for (int k0 = 0; k0 < DD_; k0 += 64) {
        __syncthreads();
        #pragma unroll
        for (int i = 0; i < 4; ++i) {
            const int row = i * 32 + w * 8 + sr;
            gl_lds16(residB + (size_t)(mBase + row) * DD_ + k0 + sgx,
                     As + i * 2048 + w * 512);
            gl_lds16(W + (size_t)(nBase + row) * DD_ + k0 + sgx,
                     Bs + i * 2048 + w * 512);
        }
        __syncthreads();
        #pragma unroll
        for (int ks = 0; ks < 2; ++ks) {
            const int fo = (((ks * 4 + quad) ^ (lan & 7)) << 3);
            bf16x8 a[4], b[4];
            #pragma unroll
            for (int mi = 0; mi < 4; ++mi)
                a[mi] = *(const bf16x8*)(As + (wm + mi * 16 + lan) * 64 + fo);
            #pragma unroll
            for (int ni = 0; ni < 4; ++ni)
                b[ni] = *(const bf16x8*)(Bs + (wn + ni * 16 + lan) * 64 + fo);
            #pragma unroll
            for (int mi = 0; mi < 4; ++mi)
                #pragma unroll
                for (int ni = 0; ni < 4; ++ni)
                    acc[mi][ni] = __builtin_amdgcn_mfma_f32_16x16x32_bf16(
                        a[mi], b[ni], acc[mi][ni], 0, 0, 0);
        }
    }
    const int headU = (nBase + wn) >> 6;
    const float scale = (z == 0) ? 0.125f * 1.44269504088896340736f : 1.0f;
    if (z < 2) {
        #pragma unroll
        for (int mi = 0; mi < 4; ++mi)
            #pragma unroll
            for (int ni = 0; ni < 4; ++ni)
                #pragma unroll
                for (int reg = 0; reg < 4; ++reg) {
                    int m = mBase + wm + mi * 16 + quad * 4 + reg;
                    int bb = m >> 11, ss = m & 2047;
                    int h = ni * 16 + lan;
                    dst[((size_t)(bb * NH_ + headU) * SS_ + ss) * 64 + h] =
                        f2bf(acc[mi][ni][reg] * scale);
                }
    } else {
        #pragma unroll
        for (int mi = 0; mi < 4; ++mi) {
            const int m0 = mBase + wm + mi * 16 + quad * 4;
            const int bb = m0 >> 11, ss0 = m0 & 2047;
            #pragma unroll
            for (int ni = 0; ni < 4; ++ni) {
                const int h = ni * 16 + lan;
                bf16x4 ob;
                #pragma unroll
                for (int reg = 0; reg < 4; ++reg)
                    ob[reg] = static_cast<__bf16>(acc[mi][ni][reg]);
                *(bf16x4*)(dst + ((size_t)(bb * NH_ + headU) * 64 + h) * SS_ + ss0) = ob;
            }
        }
    }
}

// ---------- K2: flash attention, 1024 blocks heavy-first, l via MFMA ----------
__global__ __launch_bounds__(256) void flash_mfma_kernel(
    const unsigned short* __restrict__ q,
    const unsigned short* __restrict__ k,
    const unsigned short* __restrict__ vT,
    unsigned short* __restrict__ attn)
{
    __shared__ unsigned short ldsK[2][64 * 64];
    __shared__ unsigned short ldsV[2][64 * 64];
    const int l = threadIdx.x & 63, w = threadIdx.x >> 6;   // w: 0..3
    const int quad = l >> 4, lan = l & 15;
    const int f = blockIdx.x;                               // 0..1023
    const int bn = (f & 7) | (((f >> 3) & 3) << 3);         // XCD swizzle
    const int chunk = 31 - (f >> 5);                        // heavy blocks first

    const unsigned short* Qg = q  + (size_t)bn * SS_ * 64;
    const unsigned short* Kg = k  + (size_t)bn * SS_ * 64;
    const unsigned short* Vg = vT + (size_t)bn * 64 * SS_;

    const int srl = l >> 3;
    const int sgx = (l & 7) ^ srl;

    const int qRow0 = chunk * 64 + w * 16;
    const int qAbs = qRow0 + lan;

    const unsigned short* Qr = Qg + (size_t)qAbs * 64 + quad * 8;
    bf16x8 Qf0 = *(const bf16x8*)(Qr);
    bf16x8 Qf1 = *(const bf16x8*)(Qr + 32);

    bf16x4 ones;
    #pragma unroll
    for (int i = 0; i < 4; ++i) ones[i] = static_cast<__bf16>(1.0f);

    float mrow = -INFINITY;
    floatx4 l_acc;                       // only [0] is kept consistent
    floatx4 o[4];
    #pragma unroll
    for (int i = 0; i < 4; ++i) l_acc[i] = 0.f;
    #pragma unroll
    for (int t = 0; t < 4; ++t)
        #pragma unroll
        for (int i = 0; i < 4; ++i) o[t][i] = 0.f;

    // prologue: stage kt=0 (each wave stages 16 rows of K and V)
    #pragma unroll
    for (int i = 0; i < 2; ++i) {
        const int row = w * 16 + i * 8;
        gl_lds16(Kg + (size_t)(row + srl) * 64 + sgx * 8, &ldsK[0][row * 64]);
        gl_lds16(Vg + (size_t)(row + srl) * SS_ + sgx * 8, &ldsV[0][row * 64]);
    }

    for (int kt = 0; kt <= chunk; ++kt) {
        const int kBase = kt * 64;
        const int buf = kt & 1;
        __syncthreads();
        if (kt < chunk) {
            const int kB1 = kBase + 64;
            #pragma unroll
            for (int i = 0; i < 2; ++i) {
                const int row = w * 16 + i * 8;
                gl_lds16(Kg + (size_t)(kB1 + row + srl) * 64 + sgx * 8,
                         &ldsK[buf ^ 1][row * 64]);
                gl_lds16(Vg + (size_t)(row + srl) * SS_ + kB1 + sgx * 8,
                         &ldsV[buf ^ 1][row * 64]);
            }
        }
        const unsigned short* Kb = &ldsK[buf][0];
        const unsigned short* Vb = &ldsV[buf][0];

        // S^T = K . Q^T
        floatx4 sc[4];
        #pragma unroll
        for (int nt = 0; nt < 4; ++nt) {
            const unsigned short* kr = Kb + (nt * 16 + lan) * 64;
            bf16x8 K0 = *(const bf16x8*)(kr + ((quad ^ (lan & 7)) << 3));
            bf16x8 K1 = *(const bf16x8*)(kr + (((quad + 4) ^ (lan & 7)) << 3));
            floatx4 zz; zz[0] = zz[1] = zz[2] = zz[3] = 0.f;
            sc[nt] = __builtin_amdgcn_mfma_f32_16x16x32_bf16(K0, Qf0, zz, 0, 0, 0);
            sc[nt] = __builtin_amdgcn_mfma_f32_16x16x32_bf16(K1, Qf1, sc[nt], 0, 0, 0);
        }
        if (kt == chunk) {   // diagonal: mask k > q
            #pragma unroll
            for (int nt = 0; nt < 4; ++nt)
                #pragma unroll
                for (int reg = 0; reg < 4; ++reg)
                    if (kBase + nt * 16 + quad * 4 + reg > qAbs)
                        sc[nt][reg] = -INFINITY;
        }
        // per-lane online softmax (q-col = lan); max over k needs cross-quad
        float mx = sc[0][0];
        #pragma unroll
        for (int nt = 0; nt < 4; ++nt)
            #pragma unroll
            for (int reg = 0; reg < 4; ++reg) mx = fmaxf(mx, sc[nt][reg]);
        mx = fmaxf(mx, __shfl_xor(mx, 16, 64));
        mx = fmaxf(mx, __shfl_xor(mx, 32, 64));
        const float mnew = fmaxf(mrow, mx);
        const float alpha = exp2f(mrow - mnew);
        mrow = mnew;
        bf16x4 pb[4];
        #pragma unroll
        for (int nt = 0; nt < 4; ++nt)
            #pragma unroll
            for (int reg = 0; reg < 4; ++reg)
                pb[nt][reg] = static_cast<__bf16>(exp2f(sc[nt][reg] - mnew));
        l_acc[0] *= alpha;
        #pragma unroll
        for (int t = 0; t < 4; ++t)
            #pragma unroll
            for (int i = 0; i < 4; ++i) o[t][i] *= alpha;
        // l += sum_k P (ones-column MFMAs; k spans quad*4+reg, summed in HW)
        #pragma unroll
        for (int nt = 0; nt < 4; ++nt)
            l_acc = mfma_pv(ones, pb[nt], l_acc);
        // O^T += V^T . P^T
        #pragma unroll
        for (int t = 0; t < 4; ++t) {
            const unsigned short* vr = Vb + (t * 16 + lan) * 64 + ((quad & 1) << 2);
            #pragma unroll
            for (int nt = 0; nt < 4; ++nt) {
                const int g = nt * 2 + (quad >> 1);
                bf16x4 Vf = *(const bf16x4*)(vr + ((g ^ (lan & 7)) << 3));
                o[t] = mfma_pv(Vf, pb[nt], o[t]);
            }
        }
    }
    const float rl = 1.f / l_acc[0];
    #pragma unroll
    for (int t = 0; t < 4; ++t) {
        bf16x4 ob;
        #pragma unroll
        for (int reg = 0; reg < 4; ++reg)
            ob[reg] = static_cast<__bf16>(o[t][reg] * rl);
        *(bf16x4*)(attn + ((size_t)bn * SS_ + qAbs) * 64 + t * 16 + quad * 4) = ob;
    }
}

// ---------- K3: output projection, m97 GEMM with swizzled LDS ----------
__global__ __launch_bounds__(256) void out_m97_kernel(
    const unsigned short* __restrict__ attn,
    const unsigned short* __restrict__ WOt,
    float* __restrict__ out)
{
    __shared__ unsigned short As[128 * 64];
    __shared__ unsigned short Bs[128 * 64];
    const int tid = threadIdx.x;
    const int l = tid & 63, w = tid >> 6;
    const int quad = l >> 4, lan = l & 15;
    const int mBase = blockIdx.x * 128;
    const int nBase = blockIdx.y * 128;
    const int wm = (w & 1) * 64, wn = (w >> 1) * 64;
    const int bbU = mBase >> 11;
    const int ssBase = mBase & 2047;

    floatx4 acc[4][4];
    #pragma unroll
    for (int a = 0; a < 4; ++a)
        #pragma unroll
        for (int b = 0; b < 4; ++b)
            #pragma unroll
            for (int i = 0; i < 4; ++i) acc[a][b][i] = 0.f;

    const int sr = l >> 3;
    const int sgx = ((l & 7) ^ sr) * 8;

    for (int kt = 0; kt < 16; ++kt) {
        const int k0 = kt * 64;
        __syncthreads();
        #pragma unroll
        for (int i = 0; i < 4; ++i) {
            const int row = i * 32 + w * 8 + sr;
            gl_lds16(attn + ((size_t)(bbU * NH_ + kt) * SS_ + ssBase + row) * 64 + sgx,
                     As + i * 2048 + w * 512);
            gl_lds16(WOt + (size_t)(nBase + row) * DD_ + k0 + sgx,
                     Bs + i * 2048 + w * 512);
        }
        __syncthreads();
        #pragma unroll
        for (int ks = 0; ks < 2; ++ks) {
            const int fo = (((ks * 4 + quad) ^ (lan & 7)) << 3);
            bf16x8 a[4], b[4];
            #pragma unroll
            for (int mi = 0; mi < 4; ++mi)
                a[mi] = *(const bf16x8*)(As + (wm + mi * 16 + lan) * 64 + fo);
            #pragma unroll
            for (int ni = 0; ni < 4; ++ni)
                b[ni] = *(const bf16x8*)(Bs + (wn + ni * 16 + lan) * 64 + fo);
            #pragma unroll
            for (int mi = 0; mi < 4; ++mi)
                #pragma unroll
                for (int ni = 0; ni < 4; ++ni)
                    acc[mi][ni] = __builtin_amdgcn_mfma_f32_16x16x32_bf16(
                        a[mi], b[ni], acc[mi][ni], 0, 0, 0);
        }
    }
    #pragma unroll
    for (int mi = 0; mi < 4; ++mi)
        #pragma unroll
        for (int ni = 0; ni < 4; ++ni)
            #pragma unroll
            for (int reg = 0; reg < 4; ++reg) {
                int m = mBase + wm + mi * 16 + quad * 4 + reg;
                out[(size_t)m * DD_ + nBase + wn + ni * 16 + lan] = acc[mi][ni][reg];
            }
}

extern "C" void kernel_launch(void* const* d_in, const int* in_sizes, int n_in,
                              void* d_out, int out_size, void* d_ws, size_t ws_size,
                              hipStream_t stream) {
    const float* resid = (const float*)d_in[0];
    const float* WQ    = (const float*)d_in[1];
    const float* WK    = (const float*)d_in[2];
    const float* WV    = (const float*)d_in[3];
    const float* WO    = (const float*)d_in[4];
    float* out = (float*)d_out;

    unsigned short* q      = (unsigned short*)d_ws;
    unsigned short* kk     = q      + 4194304;
    unsigned short* vT     = kk     + 4194304;
    unsigned short* attn   = vT     + 4194304;
    unsigned short* residB = attn   + 4194304;
    unsigned short* WQb    = residB + 4194304;
    unsigned short* WKb    = WQb    + 1048576;
    unsigned short* WVb    = WKb    + 1048576;
    unsigned short* WOt    = WVb    + 1048576;

    cast_bf16_kernel<<<dim3(4096, 4), 256, 0, stream>>>(
        resid, WQ, WK, WV, residB, WQb, WKb, WVb);
    wo_transpose_kernel<<<dim3(16, 16), 256, 0, stream>>>(WO, WOt);
    qkv_m97_kernel<<<dim3(32, 8, 3), 256, 0, stream>>>(
        residB, WQb, WKb, WVb, q, kk, vT);
    flash_mfma_kernel<<<dim3(1024), dim3(256), 0, stream>>>(q, kk, vT, attn);
    out_m97_kernel<<<dim3(32, 8), 256, 0, stream>>>(attn, WOt, out);
}

// Round 10
// 193.656 us; speedup vs baseline: 9.6237x; 1.0156x over previous
//
#include <hip/hip_runtime.h>
#include <math.h>

// R10: flash software pipeline — QK(kt+1) MFMAs issued BEFORE softmax(kt)
// so matrix pipe (next tile's scores) and VALU (this tile's softmax) overlap
// within one wave; K triple-buffered / V double-buffered (40KB LDS, still
// 4 blocks/CU). Uniform skip-rescale via __all(mx<=mrow) (~80% of iters).
// GEMMs (m97 + xor-swizzled LDS, R8-verified) unchanged.
// Layouts (verified R2-R9, absmax 7.8e-3):
//   x32 A-frag: m=lane&15, k=(lane>>4)*8+j ; B-frag: n=lane&15, k=(lane>>4)*8+j
//   x16 A/B-frag: idx=lane&15, k=(lane>>4)*4+j
//   C/D (all 16x16): col=lane&15, row=(lane>>4)*4+reg

#define SS_ 2048
#define DD_ 1024
#define NH_ 16
#define BN_ 32
#define BS_ 4096

typedef __bf16 bf16x8 __attribute__((ext_vector_type(8)));
typedef __bf16 bf16x4 __attribute__((ext_vector_type(4)));
typedef short shortx4 __attribute__((ext_vector_type(4)));
typedef float floatx4 __attribute__((ext_vector_type(4)));
typedef unsigned short ushortx4 __attribute__((ext_vector_type(4)));

__device__ __forceinline__ unsigned short f2bf(float f) {
    union { float f; unsigned u; } v; v.f = f;
    unsigned r = v.u + 0x7FFFu + ((v.u >> 16) & 1u);   // RNE
    return (unsigned short)(r >> 16);
}

__device__ __forceinline__ floatx4 mfma_pv(bf16x4 a, bf16x4 b, floatx4 c) {
#if __has_builtin(__builtin_amdgcn_mfma_f32_16x16x16_bf16)
    return __builtin_amdgcn_mfma_f32_16x16x16_bf16(a, b, c, 0, 0, 0);
#else
    return __builtin_amdgcn_mfma_f32_16x16x16bf16_1k(
        __builtin_bit_cast(shortx4, a), __builtin_bit_cast(shortx4, b), c, 0, 0, 0);
#endif
}

__device__ __forceinline__ void gl_lds16(const unsigned short* g, unsigned short* l) {
    __builtin_amdgcn_global_load_lds(
        (const __attribute__((address_space(1))) unsigned int*)g,
        (__attribute__((address_space(3))) unsigned int*)l, 16, 0, 0);
}

// ---------- K0a: cast resid + WQ/WK/WV to bf16 ----------
__global__ __launch_bounds__(256) void cast_bf16_kernel(
    const float* __restrict__ resid, const float* __restrict__ WQ,
    const float* __restrict__ WK, const float* __restrict__ WV,
    unsigned short* __restrict__ residB, unsigned short* __restrict__ WQb,
    unsigned short* __restrict__ WKb, unsigned short* __restrict__ WVb)
{
    const int z = blockIdx.y;
    if (z > 0 && blockIdx.x >= 1024) return;
    const float* src = (z == 0) ? resid : (z == 1) ? WQ : (z == 2) ? WK : WV;
    unsigned short* dst = (z == 0) ? residB : (z == 1) ? WQb : (z == 2) ? WKb : WVb;
    const int i = (blockIdx.x * 256 + threadIdx.x) * 4;
    float4 f = *(const float4*)(src + i);
    ushortx4 o;
    o[0] = f2bf(f.x); o[1] = f2bf(f.y); o[2] = f2bf(f.z); o[3] = f2bf(f.w);
    *(ushortx4*)(dst + i) = o;
}

// ---------- K0b: WO [kk=n*64+h][d] fp32 -> WOt [d][kk] bf16 ----------
__global__ __launch_bounds__(256) void wo_transpose_kernel(
    const float* __restrict__ WO, unsigned short* __restrict__ WOt)
{
    __shared__ float t[64][65];
    const int kk0 = blockIdx.x * 64, d0 = blockIdx.y * 64;
    #pragma unroll
    for (int it = 0; it < 16; ++it) {
        int idx = it * 256 + threadIdx.x;
        int r = idx >> 6, c = idx & 63;
        t[r][c] = WO[(kk0 + r) * DD_ + d0 + c];
    }
    __syncthreads();
    #pragma unroll
    for (int it = 0; it < 16; ++it) {
        int idx = it * 256 + threadIdx.x;
        int r = idx >> 6, c = idx & 63;
        WOt[(d0 + r) * DD_ + kk0 + c] = f2bf(t[c][r]);
    }
}

// ---------- K1: QKV projections, m97 GEMM with swizzled LDS ----------
__global__ __launch_bounds__(256) void qkv_m97_kernel(
    const unsigned short* __restrict__ residB,
    const unsigned short* __restrict__ WQb,
    const unsigned short* __restrict__ WKb,
    const unsigned short* __restrict__ WVb,
    unsigned short* __restrict__ q, unsigned short* __restrict__ kk,
    unsigned short* __restrict__ vT)
{
    __shared__ unsigned short As[128 * 64];
    __shared__ unsigned short Bs[128 * 64];
    const int tid = threadIdx.x;
    const int l = tid & 63, w = tid >> 6;
    const int quad = l >> 4, lan = l & 15;
    const int z = blockIdx.z;
    const unsigned short* W = (z == 0) ? WQb : (z == 1) ? WKb : WVb;
    unsigned short* dst = (z == 0) ? q : (z == 1) ? kk : vT;
    const int mBase = blockIdx.x * 128;
    const int nBase = blockIdx.y * 128;
    const int wm = (w & 1) * 64, wn = (w >> 1) * 64;

    floatx4 acc[4][4];
    #pragma unroll
    for (int a = 0; a < 4; ++a)
        #pragma unroll
        for (int b = 0; b < 4; ++b)
            #pragma unroll
            for (int i = 0; i < 4; ++i) acc[a][b][i] = 0.f;

    const int sr = l >> 3;
    const int sgx = ((l & 7) ^ sr) * 8;

    for (int k0 = 0; k0 < DD_; k0 += 64) {
        __syncthreads();
        #pragma unroll
        for (int i = 0; i < 4; ++i) {
            const int row = i * 32 + w * 8 + sr;
            gl_lds16(residB + (size_t)(mBase + row) * DD_ + k0 + sgx,
                     As + i * 2048 + w * 512);
            gl_lds16(W + (size_t)(nBase + row) * DD_ + k0 + sgx,
                     Bs + i * 2048 + w * 512);
        }
        __syncthreads();
        #pragma unroll
        for (int ks = 0; ks < 2; ++ks) {
            const int fo = (((ks * 4 + quad) ^ (lan & 7)) << 3);
            bf16x8 a[4], b[4];
            #pragma unroll
            for (int mi = 0; mi < 4; ++mi)
                a[mi] = *(const bf16x8*)(As + (wm + mi * 16 + lan) * 64 + fo);
            #pragma unroll
            for (int ni = 0; ni < 4; ++ni)
                b[ni] = *(const bf16x8*)(Bs + (wn + ni * 16 + lan) * 64 + fo);
            #pragma unroll
            for (int mi = 0; mi < 4; ++mi)
                #pragma unroll
                for (int ni = 0; ni < 4; ++ni)
                    acc[mi][ni] = __builtin_amdgcn_mfma_f32_16x16x32_bf16(
                        a[mi], b[ni], acc[mi][ni], 0, 0, 0);
        }
    }
    const int headU = (nBase + wn) >> 6;
    const float scale = (z == 0) ? 0.125f * 1.44269504088896340736f : 1.0f;
    if (z < 2) {
        #pragma unroll
        for (int mi = 0; mi < 4; ++mi)
            #pragma unroll
            for (int ni = 0; ni < 4; ++ni)
                #pragma unroll
                for (int reg = 0; reg < 4; ++reg) {
                    int m = mBase + wm + mi * 16 + quad * 4 + reg;
                    int bb = m >> 11, ss = m & 2047;
                    int h = ni * 16 + lan;
                    dst[((size_t)(bb * NH_ + headU) * SS_ + ss) * 64 + h] =
                        f2bf(acc[mi][ni][reg] * scale);
                }
    } else {
        #pragma unroll
        for (int mi = 0; mi < 4; ++mi) {
            const int m0 = mBase + wm + mi * 16 + quad * 4;
            const int bb = m0 >> 11, ss0 = m0 & 2047;
            #pragma unroll
            for (int ni = 0; ni < 4; ++ni) {
                const int h = ni * 16 + lan;
                bf16x4 ob;
                #pragma unroll
                for (int reg = 0; reg < 4; ++reg)
                    ob[reg] = static_cast<__bf16>(acc[mi][ni][reg]);
                *(bf16x4*)(dst + ((size_t)(bb * NH_ + headU) * 64 + h) * SS_ + ss0) = ob;
            }
        }
    }
}

// ---------- K2: flash attention, software-pipelined QK ----------
__global__ __launch_bounds__(256, 4) void flash_mfma_kernel(
    const unsigned short* __restrict__ q,
    const unsigned short* __restrict__ k,
    const unsigned short* __restrict__ vT,
    unsigned short* __restrict__ attn)
{
    __shared__ unsigned short ldsK[3][64 * 64];   // triple: QK runs one ahead
    __shared__ unsigned short ldsV[2][64 * 64];
    const int l = threadIdx.x & 63, w = threadIdx.x >> 6;   // w: 0..3
    const int quad = l >> 4, lan = l & 15;
    const int f = blockIdx.x;                               // 0..1023
    const int bn = (f & 7) | (((f >> 3) & 3) << 3);         // XCD swizzle
    const int chunk = 31 - (f >> 5);                        // heavy blocks first

    const unsigned short* Qg = q  + (size_t)bn * SS_ * 64;
    const unsigned short* Kg = k  + (size_t)bn * SS_ * 64;
    const unsigned short* Vg = vT + (size_t)bn * 64 * SS_;

    const int srl = l >> 3;
    const int sgx = (l & 7) ^ srl;

    const int qRow0 = chunk * 64 + w * 16;
    const int qAbs = qRow0 + lan;

    const unsigned short* Qr = Qg + (size_t)qAbs * 64 + quad * 8;
    bf16x8 Qf0 = *(const bf16x8*)(Qr);
    bf16x8 Qf1 = *(const bf16x8*)(Qr + 32);

    bf16x4 ones;
    #pragma unroll
    for (int i = 0; i < 4; ++i) ones[i] = static_cast<__bf16>(1.0f);

    float mrow = -INFINITY;
    floatx4 l_acc;                       // only [0] kept consistent
    floatx4 o[4];
    #pragma unroll
    for (int i = 0; i < 4; ++i) l_acc[i] = 0.f;
    #pragma unroll
    for (int t = 0; t < 4; ++t)
        #pragma unroll
        for (int i = 0; i < 4; ++i) o[t][i] = 0.f;

    // staging helpers: each wave stages 16 rows (2x gl_lds16) per tile
    #define STAGE_K(kt_, buf_)                                                  \
        { const int row0_ = w * 16, kB_ = (kt_) * 64;                           \
          gl_lds16(Kg + (size_t)(kB_ + row0_ + srl) * 64 + sgx * 8,             \
                   &ldsK[buf_][row0_ * 64]);                                    \
          gl_lds16(Kg + (size_t)(kB_ + row0_ + 8 + srl) * 64 + sgx * 8,         \
                   &ldsK[buf_][(row0_ + 8) * 64]); }
    #define STAGE_V(kt_, buf_)                                                  \
        { const int row0_ = w * 16, kB_ = (kt_) * 64;                           \
          gl_lds16(Vg + (size_t)(row0_ + srl) * SS_ + kB_ + sgx * 8,            \
                   &ldsV[buf_][row0_ * 64]);                                    \
          gl_lds16(Vg + (size_t)(row0_ + 8 + srl) * SS_ + kB_ + sgx * 8,        \
                   &ldsV[buf_][(row0_ + 8) * 64]); }
    #define QK_TILE(dst_, buf_)                                                 \
        { const unsigned short* Kb_ = &ldsK[buf_][0];                           \
          _Pragma("unroll")                                                     \
          for (int nt = 0; nt < 4; ++nt) {                                      \
              const unsigned short* kr_ = Kb_ + (nt * 16 + lan) * 64;           \
              bf16x8 K0_ = *(const bf16x8*)(kr_ + ((quad ^ (lan & 7)) << 3));   \
              bf16x8 K1_ = *(const bf16x8*)(kr_ + (((quad + 4) ^ (lan & 7)) << 3)); \
              floatx4 zz_; zz_[0] = zz_[1] = zz_[2] = zz_[3] = 0.f;             \
              dst_[nt] = __builtin_amdgcn_mfma_f32_16x16x32_bf16(K0_, Qf0, zz_, 0, 0, 0); \
              dst_[nt] = __builtin_amdgcn_mfma_f32_16x16x32_bf16(K1_, Qf1, dst_[nt], 0, 0, 0); } }

    // prologue: stage(0); barrier; stage K(1); scCur = QK(0)
    STAGE_K(0, 0);
    STAGE_V(0, 0);
    __syncthreads();
    if (chunk >= 1) STAGE_K(1, 1);
    floatx4 scCur[4], scNext[4];
    QK_TILE(scCur, 0);

    for (int kt = 0; kt <= chunk; ++kt) {
        const int kBase = kt * 64;
        __syncthreads();   // stage(kt+1) visible; prior readers drained
        if (kt + 2 <= chunk) STAGE_K(kt + 2, (kt + 2) % 3);
        if (kt + 1 <= chunk) {
            STAGE_V(kt + 1, (kt + 1) & 1);
            QK_TILE(scNext, (kt + 1) % 3);   // issue next QK before softmax
        }
        if (kt == chunk) {   // diagonal: mask k > q
            #pragma unroll
            for (int nt = 0; nt < 4; ++nt)
                #pragma unroll
                for (int reg = 0; reg < 4; ++reg)
                    if (kBase + nt * 16 + quad * 4 + reg > qAbs)
                        scCur[nt][reg] = -INFINITY;
        }
        // softmax on scCur (computed one iter ago -> MFMA long done)
        float mx = scCur[0][0];
        #pragma unroll
        for (int nt = 0; nt < 4; ++nt)
            #pragma unroll
            for (int reg = 0; reg < 4; ++reg) mx = fmaxf(mx, scCur[nt][reg]);
        mx = fmaxf(mx, __shfl_xor(mx, 16, 64));
        mx = fmaxf(mx, __shfl_xor(mx, 32, 64));
        const float mnew = fmaxf(mrow, mx);
        if (!__all(mx <= mrow)) {        // uniform skip: max unchanged on all lanes
            const float alpha = exp2f(mrow - mnew);
            l_acc[0] *= alpha;
            #pragma unroll
            for (int t = 0; t < 4; ++t)
                #pragma unroll
                for (int i = 0; i < 4; ++i) o[t][i] *= alpha;
        }
        mrow = mnew;
        bf16x4 pb[4];
        #pragma unroll
        for (int nt = 0; nt < 4; ++nt)
            #pragma unroll
            for (int reg = 0; reg < 4; ++reg)
                pb[nt][reg] = static_cast<__bf16>(exp2f(scCur[nt][reg] - mnew));
        // l += sum_k P (ones-column MFMAs)
        #pragma unroll
        for (int nt = 0; nt < 4; ++nt)
            l_acc = mfma_pv(ones, pb[nt], l_acc);
        // O^T += V^T . P^T
        const unsigned short* Vb = &ldsV[kt & 1][0];
        #pragma unroll
        for (int t = 0; t < 4; ++t) {
            const unsigned short* vr = Vb + (t * 16 + lan) * 64 + ((quad & 1) << 2);
            #pragma unroll
            for (int nt = 0; nt < 4; ++nt) {
                const int g = nt * 2 + (quad >> 1);
                bf16x4 Vf = *(const bf16x4*)(vr + ((g ^ (lan & 7)) << 3));
                o[t] = mfma_pv(Vf, pb[nt], o[t]);
            }
        }
        #pragma unroll
        for (int nt = 0; nt < 4; ++nt) scCur[nt] = scNext[nt];
    }
    const float rl = 1.f / l_acc[0];
    #pragma unroll
    for (int t = 0; t < 4; ++t) {
        bf16x4 ob;
        #pragma unroll
        for (int reg = 0; reg < 4; ++reg)
            ob[reg] = static_cast<__bf16>(o[t][reg] * rl);
        *(bf16x4*)(attn + ((size_t)bn * SS_ + qAbs) * 64 + t * 16 + quad * 4) = ob;
    }
    #undef STAGE_K
    #undef STAGE_V
    #undef QK_TILE
}

// ---------- K3: output projection, m97 GEMM with swizzled LDS ----------
__global__ __launch_bounds__(256) void out_m97_kernel(
    const unsigned short* __restrict__ attn,
    const unsigned short* __restrict__ WOt,
    float* __restrict__ out)
{
    __shared__ unsigned short As[128 * 64];
    __shared__ unsigned short Bs[128 * 64];
    const int tid = threadIdx.x;
    const int l = tid & 63, w = tid >> 6;
    const int quad = l >> 4, lan = l & 15;
    const int mBase = blockIdx.x * 128;
    const int nBase = blockIdx.y * 128;
    const int wm = (w & 1) * 64, wn = (w >> 1) * 64;
    const int bbU = mBase >> 11;
    const int ssBase = mBase & 2047;

    floatx4 acc[4][4];
    #pragma unroll
    for (int a = 0; a < 4; ++a)
        #pragma unroll
        for (int b = 0; b < 4; ++b)
            #pragma unroll
            for (int i = 0; i < 4; ++i) acc[a][b][i] = 0.f;

    const int sr = l >> 3;
    const int sgx = ((l & 7) ^ sr) * 8;

    for (int kt = 0; kt < 16; ++kt) {
        const int k0 = kt * 64;
        __syncthreads();
        #pragma unroll
        for (int i = 0; i < 4; ++i) {
            const int row = i * 32 + w * 8 + sr;
            gl_lds16(attn + ((size_t)(bbU * NH_ + kt) * SS_ + ssBase + row) * 64 + sgx,
                     As + i * 2048 + w * 512);
            gl_lds16(WOt + (size_t)(nBase + row) * DD_ + k0 + sgx,
                     Bs + i * 2048 + w * 512);
        }
        __syncthreads();
        #pragma unroll
        for (int ks = 0; ks < 2; ++ks) {
            const int fo = (((ks * 4 + quad) ^ (lan & 7)) << 3);
            bf16x8 a[4], b[4];
            #pragma unroll
            for (int mi = 0; mi < 4; ++mi)
                a[mi] = *(const bf16x8*)(As + (wm + mi * 16 + lan) * 64 + fo);
            #pragma unroll
            for (int ni = 0; ni < 4; ++ni)
                b[ni] = *(const bf16x8*)(Bs + (wn + ni * 16 + lan) * 64 + fo);
            #pragma unroll
            for (int mi = 0; mi < 4; ++mi)
                #pragma unroll
                for (int ni = 0; ni < 4; ++ni)
                    acc[mi][ni] = __builtin_amdgcn_mfma_f32_16x16x32_bf16(
                        a[mi], b[ni], acc[mi][ni], 0, 0, 0);
        }
    }
    #pragma unroll
    for (int mi = 0; mi < 4; ++mi)
        #pragma unroll
        for (int ni = 0; ni < 4; ++ni)
            #pragma unroll
            for (int reg = 0; reg < 4; ++reg) {
                int m = mBase + wm + mi * 16 + quad * 4 + reg;
                out[(size_t)m * DD_ + nBase + wn + ni * 16 + lan] = acc[mi][ni][reg];
            }
}

extern "C" void kernel_launch(void* const* d_in, const int* in_sizes, int n_in,
                              void* d_out, int out_size, void* d_ws, size_t ws_size,
                              hipStream_t stream) {
    const float* resid = (const float*)d_in[0];
    const float* WQ    = (const float*)d_in[1];
    const float* WK    = (const float*)d_in[2];
    const float* WV    = (const float*)d_in[3];
    const float* WO    = (const float*)d_in[4];
    float* out = (float*)d_out;

    unsigned short* q      = (unsigned short*)d_ws;
    unsigned short* kk     = q      + 4194304;
    unsigned short* vT     = kk     + 4194304;
    unsigned short* attn   = vT     + 4194304;
    unsigned short* residB = attn   + 4194304;
    unsigned short* WQb    = residB + 4194304;
    unsigned short* WKb    = WQb    + 1048576;
    unsigned short* WVb    = WKb    + 1048576;
    unsigned short* WOt    = WVb    + 1048576;

    cast_bf16_kernel<<<dim3(4096, 4), 256, 0, stream>>>(
        resid, WQ, WK, WV, residB, WQb, WKb, WVb);
    wo_transpose_kernel<<<dim3(16, 16), 256, 0, stream>>>(WO, WOt);
    qkv_m97_kernel<<<dim3(32, 8, 3), 256, 0, stream>>>(
        residB, WQb, WKb, WVb, q, kk, vT);
    flash_mfma_kernel<<<dim3(1024), dim3(256), 0, stream>>>(q, kk, vT, attn);
    out_m97_kernel<<<dim3(32, 8), 256, 0, stream>>>(attn, WOt, out);
}